// Round 32
// baseline (1073.998 us; speedup 1.0000x reference)
//
#include <hip/hip_runtime.h>
#include <math.h>

#define TPB 256
#define NGRAPH 2048

typedef __attribute__((ext_vector_type(8))) short bf16x8;
typedef __attribute__((ext_vector_type(4))) float f32x4;

__device__ __forceinline__ unsigned short f2bf(float f) {
  unsigned u = __float_as_uint(f);
  unsigned r = (u + 0x7FFF + ((u >> 16) & 1)) >> 16;
  return (unsigned short)r;
}
__device__ __forceinline__ float bf2f(unsigned short h) {
  return __uint_as_float(((unsigned)h) << 16);
}
__device__ __forceinline__ float bflo(unsigned u) {
  return __uint_as_float(u << 16);
}
__device__ __forceinline__ float bfhi(unsigned u) {
  return __uint_as_float(u & 0xFFFF0000u);
}

#define GLOAD_LDS16(G, L) \
  __builtin_amdgcn_global_load_lds((const __attribute__((address_space(1))) unsigned int*)(G), \
                                   (__attribute__((address_space(3))) unsigned int*)(L), 16, 0, 0)

// ---------------- init / degree / histograms ----------------
__global__ void k_init(float* __restrict__ deg, int* __restrict__ cnt,
                       int* __restrict__ cntg, float* __restrict__ statsAll,
                       float* __restrict__ statsP, int* __restrict__ cnts, int N) {
  int i = blockIdx.x * TPB + threadIdx.x;
  if (i < N) { deg[i] = 1.0f; cnt[i] = 0; }
  if (i < NGRAPH) cntg[i] = 0;
  if (i < 2048) statsAll[i] = 0.f;
  if (i < 12288) statsP[i] = 0.f;
  if (i < 4) cnts[i] = 0;
}

// fused: edge-degree histogram (over E) + graph-size histogram (over N)
__global__ void k_hist(const int* __restrict__ dst, float* __restrict__ deg,
                       int* __restrict__ cnt, const int* __restrict__ batch,
                       int* __restrict__ cntg, int E, int N) {
  int i = blockIdx.x * TPB + threadIdx.x;
  if (i < E) {
    int d = dst[i];
    atomicAdd(&deg[d], 1.0f);
    atomicAdd(&cnt[d], 1);
  }
  if (i < N) atomicAdd(&cntg[batch[i]], 1);
}

// ---------------- scans ----------------
__global__ void k_scan1(const int* __restrict__ in, int* __restrict__ out,
                        int* __restrict__ bsum, int n) {
  __shared__ int ts[256];
  int tid = threadIdx.x;
  int base = blockIdx.x * 1024 + tid * 4;
  int v0 = (base + 0 < n) ? in[base + 0] : 0;
  int v1 = (base + 1 < n) ? in[base + 1] : 0;
  int v2 = (base + 2 < n) ? in[base + 2] : 0;
  int v3 = (base + 3 < n) ? in[base + 3] : 0;
  int s = v0 + v1 + v2 + v3;
  int run = s;
  ts[tid] = run; __syncthreads();
  for (int off = 1; off < 256; off <<= 1) {
    int add = (tid >= off) ? ts[tid - off] : 0;
    __syncthreads();
    run += add; ts[tid] = run; __syncthreads();
  }
  int acc = run - s;
  if (base + 0 < n) out[base + 0] = acc; acc += v0;
  if (base + 1 < n) out[base + 1] = acc; acc += v1;
  if (base + 2 < n) out[base + 2] = acc; acc += v2;
  if (base + 3 < n) out[base + 3] = acc;
  if (tid == 255) bsum[blockIdx.x] = run;
}

// dual single-block exclusive scan: block 0 scans (inA,nA)->dstA, block 1
// scans (inB,nB)->dstB. Both inputs are ready when this launches.
__global__ void k_scan_small2(const int* __restrict__ inA, int* __restrict__ dstA, int nA,
                              const int* __restrict__ inB, int* __restrict__ dstB, int nB) {
  __shared__ int ts[256];
  const int* in = (blockIdx.x == 0) ? inA : inB;
  int* dst      = (blockIdx.x == 0) ? dstA : dstB;
  int n         = (blockIdx.x == 0) ? nA : nB;
  int tid = threadIdx.x;
  int chunk = (n + 255) >> 8;
  int start = tid * chunk;
  int s = 0;
  for (int j = 0; j < chunk; ++j) { int idx = start + j; if (idx < n) s += in[idx]; }
  int run = s;
  ts[tid] = run; __syncthreads();
  for (int off = 1; off < 256; off <<= 1) {
    int add = (tid >= off) ? ts[tid - off] : 0;
    __syncthreads();
    run += add; ts[tid] = run; __syncthreads();
  }
  int acc = run - s;
  for (int j = 0; j < chunk; ++j) {
    int idx = start + j;
    if (idx < n) { dst[idx] = acc; acc += in[idx]; }
  }
  if (tid == 255) dst[n] = run;
}

// scan finalize + fused rsqrt(deg) -> dis (deg final since k_hist completed)
__global__ void k_scan3(int* __restrict__ rs, const int* __restrict__ bsumx,
                        int* __restrict__ cursor, float* __restrict__ dis,
                        int n, int total) {
  int i = blockIdx.x * TPB + threadIdx.x;
  if (i < n) {
    int v = rs[i] + bsumx[i >> 10];
    rs[i] = v; cursor[i] = v;
    dis[i] = rsqrtf(dis[i]);
  }
  if (i == 0) rs[n] = total;
}

__global__ void k_scatter(const int* __restrict__ src, const int* __restrict__ dst,
                          int* __restrict__ cursor, int* __restrict__ es, int E) {
  int e = blockIdx.x * TPB + threadIdx.x;
  if (e < E) {
    int d = dst[e];
    int p = atomicAdd(&cursor[d], 1);
    es[p] = src[e];
  }
}

// ------- weight prep: all 3 layers in one launch (grid 768) ----------------
// K=64-blocked transposed layout, swizzle pre-baked.
__global__ __launch_bounds__(256) void k_wprep2(const float* __restrict__ W2,
    const float* __restrict__ W3, const float* __restrict__ W4,
    unsigned short* __restrict__ Wblk) {
  int L = blockIdx.x >> 8;          // 0..2
  int c = blockIdx.x & 255;
  int k = threadIdx.x;
  const float* W = (L == 0) ? W2 : (L == 1) ? W3 : W4;
  float w = W[k * 256 + c];
  int t = k >> 6, kl = k & 63;
  Wblk[L * 65536 + t * 16384 + c * 64 + (kl ^ ((c & 7) << 3))] = f2bf(w);
}

// ---------------- layer-1 aggregation on D=8 (fp32) ----------------
__global__ void k_agg8(const float* __restrict__ x, const float* __restrict__ dis,
                       const int* __restrict__ rs, const int* __restrict__ es,
                       float* __restrict__ xa8, int N) {
  int t = blockIdx.x * TPB + threadIdx.x;
  int n = t >> 3, c = t & 7;
  if (n >= N) return;
  int e0 = rs[n], e1 = rs[n + 1];
  float acc = 0.f;
  for (int e = e0; e < e1; ++e) {
    int s = es[e];
    acc += dis[s] * x[s * 8 + c];
  }
  float dn = dis[n];
  xa8[n * 8 + c] = dn * acc + dn * dn * x[n * 8 + c];
}

// y[N,256] = xa8[N,8] @ W[8,256] + b, fused BN stats + last-block scaleshift
__global__ __launch_bounds__(256) void k_gemm8(const float* __restrict__ A,
    const float* __restrict__ W, const float* __restrict__ b,
    unsigned short* __restrict__ Ybf, float* __restrict__ stats,
    const float* __restrict__ g, const float* __restrict__ be,
    float* __restrict__ ssOut, int* __restrict__ counter, int N) {
  __shared__ float Ws[8 * 256];
  __shared__ float bs[256];
  __shared__ float rows[64 * 8];
  int tid = threadIdx.x;
  int row0 = blockIdx.x * 64;
  for (int j = 0; j < 8; ++j) Ws[tid + j * 256] = W[tid + j * 256];
  bs[tid] = b[tid];
  int lim = N * 8;
  int o0 = row0 * 8 + tid, o1 = o0 + 256;
  rows[tid] = (o0 < lim) ? A[o0] : 0.f;
  rows[tid + 256] = (o1 < lim) ? A[o1] : 0.f;
  __syncthreads();
  float bb = bs[tid];
  float s = 0.f, s2 = 0.f;
  for (int r = 0; r < 64; r += 2) {
    int rowA = row0 + r, rowB = rowA + 1;
    float a0 = bb, a1 = bb;
#pragma unroll
    for (int k = 0; k < 8; ++k) {
      a0 = fmaf(rows[r * 8 + k], Ws[k * 256 + tid], a0);
      a1 = fmaf(rows[r * 8 + 8 + k], Ws[k * 256 + tid], a1);
    }
    if (rowA < N) {
      Ybf[(size_t)rowA * 256 + tid] = f2bf(a0);
      s += a0; s2 += a0 * a0;
    }
    if (rowB < N) {
      Ybf[(size_t)rowB * 256 + tid] = f2bf(a1);
      s += a1; s2 += a1 * a1;
    }
  }
  atomicAdd(&stats[tid], s);
  atomicAdd(&stats[256 + tid], s2);
  // ---- last block computes BN scale/shift (replaces k_scaleshift) ----
  __threadfence();
  __syncthreads();
  __shared__ int isLast;
  if (tid == 0) isLast = (atomicAdd(counter, 1) == (int)gridDim.x - 1);
  __syncthreads();
  if (isLast) {
    float ts = atomicAdd(&stats[tid], 0.0f);        // coherent read
    float ts2 = atomicAdd(&stats[256 + tid], 0.0f);
    float inv = 1.0f / (float)N;
    float mean = ts * inv;
    float var = fmaxf(ts2 * inv - mean * mean, 0.f);
    float sc = g[tid] * rsqrtf(var + 1e-5f);
    ssOut[tid] = sc;
    ssOut[256 + tid] = be[tid] - mean * sc;
  }
}

// ------- fused BN+ReLU aggregation, half-wave per node (r22-measured) ------
__global__ __launch_bounds__(256) void k_agg_bn(const unsigned short* __restrict__ Ybf,
    const float* __restrict__ ss, const float* __restrict__ dis,
    const int* __restrict__ rs, const int* __restrict__ es,
    unsigned short* __restrict__ Ahi, int N) {
  int l32 = threadIdx.x & 31;
  int n = blockIdx.x * 8 + (threadIdx.x >> 5);
  if (n >= N) return;
  int c = l32 * 8;
  float4 sc0 = *(const float4*)&ss[c];
  float4 sc1 = *(const float4*)&ss[c + 4];
  float4 sh0 = *(const float4*)&ss[256 + c];
  float4 sh1 = *(const float4*)&ss[256 + c + 4];
  int e0 = rs[n], e1 = rs[n + 1];
  float a0 = 0.f, a1 = 0.f, a2 = 0.f, a3 = 0.f;
  float a4 = 0.f, a5 = 0.f, a6 = 0.f, a7 = 0.f;
#define BNR8(Q, d)                                                           \
  {                                                                          \
    a0 += (d) * fmaxf(fmaf(bflo(Q.x), sc0.x, sh0.x), 0.f);                   \
    a1 += (d) * fmaxf(fmaf(bfhi(Q.x), sc0.y, sh0.y), 0.f);                   \
    a2 += (d) * fmaxf(fmaf(bflo(Q.y), sc0.z, sh0.z), 0.f);                   \
    a3 += (d) * fmaxf(fmaf(bfhi(Q.y), sc0.w, sh0.w), 0.f);                   \
    a4 += (d) * fmaxf(fmaf(bflo(Q.z), sc1.x, sh1.x), 0.f);                   \
    a5 += (d) * fmaxf(fmaf(bfhi(Q.z), sc1.y, sh1.y), 0.f);                   \
    a6 += (d) * fmaxf(fmaf(bflo(Q.w), sc1.z, sh1.z), 0.f);                   \
    a7 += (d) * fmaxf(fmaf(bfhi(Q.w), sc1.w, sh1.w), 0.f);                   \
  }
  int e = e0;
  for (; e + 2 <= e1; e += 2) {
    int s0 = es[e], s1 = es[e + 1];
    float d0 = dis[s0], d1 = dis[s1];
    uint4 y0 = *(const uint4*)&Ybf[(size_t)s0 * 256 + c];
    uint4 y1 = *(const uint4*)&Ybf[(size_t)s1 * 256 + c];
    BNR8(y0, d0);
    BNR8(y1, d1);
  }
  if (e < e1) {
    int s0 = es[e];
    float d0 = dis[s0];
    uint4 y0 = *(const uint4*)&Ybf[(size_t)s0 * 256 + c];
    BNR8(y0, d0);
  }
#undef BNR8
  float dn = dis[n];
  float dn2 = dn * dn;
  uint4 yb = *(const uint4*)&Ybf[(size_t)n * 256 + c];
  float r0 = dn * a0 + dn2 * fmaxf(fmaf(bflo(yb.x), sc0.x, sh0.x), 0.f);
  float r1 = dn * a1 + dn2 * fmaxf(fmaf(bfhi(yb.x), sc0.y, sh0.y), 0.f);
  float r2 = dn * a2 + dn2 * fmaxf(fmaf(bflo(yb.y), sc0.z, sh0.z), 0.f);
  float r3 = dn * a3 + dn2 * fmaxf(fmaf(bfhi(yb.y), sc0.w, sh0.w), 0.f);
  float r4 = dn * a4 + dn2 * fmaxf(fmaf(bflo(yb.z), sc1.x, sh1.x), 0.f);
  float r5 = dn * a5 + dn2 * fmaxf(fmaf(bfhi(yb.z), sc1.y, sh1.y), 0.f);
  float r6 = dn * a6 + dn2 * fmaxf(fmaf(bflo(yb.w), sc1.z, sh1.z), 0.f);
  float r7 = dn * a7 + dn2 * fmaxf(fmaf(bfhi(yb.w), sc1.w, sh1.w), 0.f);
  uint4 o;
  o.x = (unsigned)f2bf(r0) | ((unsigned)f2bf(r1) << 16);
  o.y = (unsigned)f2bf(r2) | ((unsigned)f2bf(r3) << 16);
  o.z = (unsigned)f2bf(r4) | ((unsigned)f2bf(r5) << 16);
  o.w = (unsigned)f2bf(r6) | ((unsigned)f2bf(r7) << 16);
  *(uint4*)&Ahi[(size_t)n * 256 + c] = o;
}

// ---------------- MFMA GEMM + last-block scaleshift ------------------------
__global__ __launch_bounds__(256) void k_gemm_mfma(
    const unsigned short* __restrict__ A,
    const unsigned short* __restrict__ Wblk,
    const float* __restrict__ bias, unsigned short* __restrict__ Ybf,
    float* __restrict__ statsP,
    const float* __restrict__ g, const float* __restrict__ be,
    float* __restrict__ ssOut, int* __restrict__ counter, int M) {
  __shared__ unsigned short Wlds[16384];  // 32KB W slab / epilogue stage
  __shared__ float bstats[512];
  const int tid = threadIdx.x;
  const int lane = tid & 63;
  const int w = tid >> 6;
  const int l15 = lane & 15, lg = lane >> 4;
  const int r0 = blockIdx.x * 64 + w * 16;

  bstats[tid] = 0.f;
  bstats[tid + 256] = 0.f;

  const unsigned short* Ap = A + (size_t)(r0 + l15) * 256 + lg * 8;

  f32x4 acc[16] = {};
#pragma unroll
  for (int t = 0; t < 4; ++t) {
#pragma unroll
    for (int it = 0; it < 8; ++it)
      GLOAD_LDS16(Wblk + t * 16384 + it * 2048 + tid * 8,
                  &Wlds[it * 2048 + tid * 8]);
    bf16x8 a0 = *(const bf16x8*)(Ap + t * 64);
    bf16x8 a1 = *(const bf16x8*)(Ap + t * 64 + 32);
    asm volatile("s_waitcnt vmcnt(0)" ::: "memory");
    __builtin_amdgcn_s_barrier();
#pragma unroll
    for (int kk2 = 0; kk2 < 2; ++kk2) {
      bf16x8 a = kk2 ? a1 : a0;
#pragma unroll
      for (int n = 0; n < 16; ++n) {
        int c = n * 16 + l15;
        bf16x8 b = *(const bf16x8*)&Wlds[c * 64 +
                     ((kk2 * 32 + lg * 8) ^ ((l15 & 7) << 3))];
        acc[n] = __builtin_amdgcn_mfma_f32_16x16x32_bf16(a, b, acc[n], 0, 0, 0);
      }
    }
    asm volatile("s_waitcnt lgkmcnt(0)" ::: "memory");
    __builtin_amdgcn_s_barrier();
  }

  unsigned short* stage = Wlds;  // 64 rows x 256 cols bf16 = 32KB
#pragma unroll
  for (int n = 0; n < 16; ++n) {
    int col = n * 16 + l15;
    float bv = bias[col];
    float s = 0.f, s2 = 0.f;
    f32x4 v = acc[n];
#pragma unroll
    for (int j = 0; j < 4; ++j) {
      float val = v[j] + bv;
      int rl = w * 16 + lg * 4 + j;
      stage[rl * 256 + col] = f2bf(val);
      if (blockIdx.x * 64 + rl < M) { s += val; s2 += val * val; }
    }
    s += __shfl_xor(s, 16);  s += __shfl_xor(s, 32);
    s2 += __shfl_xor(s2, 16); s2 += __shfl_xor(s2, 32);
    if (lg == 0) {
      atomicAdd(&bstats[col], s);
      atomicAdd(&bstats[256 + col], s2);
    }
  }
  __syncthreads();
#pragma unroll
  for (int it = 0; it < 8; ++it) {
    int idx = it * 256 + tid;
    int rl = idx >> 5;
    int c16 = idx & 31;
    int grow = blockIdx.x * 64 + rl;
    if (grow < M)
      *(int4*)((char*)Ybf + (size_t)grow * 512 + c16 * 16) =
          *(const int4*)((const char*)stage + rl * 512 + c16 * 16);
  }
  float* sp = statsP + (blockIdx.x & 7) * 512;
  atomicAdd(&sp[tid], bstats[tid]);
  atomicAdd(&sp[256 + tid], bstats[256 + tid]);
  // ---- last block computes BN scale/shift (replaces k_scaleshift) ----
  __threadfence();
  __syncthreads();
  __shared__ int isLast;
  if (tid == 0) isLast = (atomicAdd(counter, 1) == (int)gridDim.x - 1);
  __syncthreads();
  if (isLast) {
    float s = 0.f, s2 = 0.f;
#pragma unroll
    for (int p = 0; p < 8; ++p) {
      s += atomicAdd(&statsP[p * 512 + tid], 0.0f);        // coherent reads
      s2 += atomicAdd(&statsP[p * 512 + 256 + tid], 0.0f);
    }
    float inv = 1.0f / (float)M;
    float mean = s * inv;
    float var = fmaxf(s2 * inv - mean * mean, 0.f);
    float sc = g[tid] * rsqrtf(var + 1e-5f);
    ssOut[tid] = sc;
    ssOut[256 + tid] = be[tid] - mean * sc;
  }
}

// ---------------- pooling with fused BN+ReLU, vectorized (r29-measured) -----
__global__ __launch_bounds__(256) void k_pool(const unsigned short* __restrict__ Ybf,
    const float* __restrict__ ss, const int* __restrict__ gstart,
    float* __restrict__ pooled) {
  __shared__ float redS[8][256];
  __shared__ float redM[8][256];
  int g = blockIdx.x;
  int tid = threadIdx.x;
  int grp = tid >> 5;      // 0..7 row-group
  int l32 = tid & 31;
  int c = l32 * 8;
  float4 sc0 = *(const float4*)&ss[c];
  float4 sc1 = *(const float4*)&ss[c + 4];
  float4 sh0 = *(const float4*)&ss[256 + c];
  float4 sh1 = *(const float4*)&ss[256 + c + 4];
  int n0 = gstart[g], n1 = gstart[g + 1];
  float s0 = 0.f, s1 = 0.f, s2 = 0.f, s3 = 0.f, s4 = 0.f, s5 = 0.f, s6 = 0.f, s7 = 0.f;
  float m0 = 0.f, m1 = 0.f, m2 = 0.f, m3 = 0.f, m4 = 0.f, m5 = 0.f, m6 = 0.f, m7 = 0.f;
  for (int n = n0 + grp; n < n1; n += 8) {
    uint4 y = *(const uint4*)&Ybf[(size_t)n * 256 + c];
    float v0 = fmaxf(fmaf(bflo(y.x), sc0.x, sh0.x), 0.f);
    float v1 = fmaxf(fmaf(bfhi(y.x), sc0.y, sh0.y), 0.f);
    float v2 = fmaxf(fmaf(bflo(y.y), sc0.z, sh0.z), 0.f);
    float v3 = fmaxf(fmaf(bfhi(y.y), sc0.w, sh0.w), 0.f);
    float v4 = fmaxf(fmaf(bflo(y.z), sc1.x, sh1.x), 0.f);
    float v5 = fmaxf(fmaf(bfhi(y.z), sc1.y, sh1.y), 0.f);
    float v6 = fmaxf(fmaf(bflo(y.w), sc1.z, sh1.z), 0.f);
    float v7 = fmaxf(fmaf(bfhi(y.w), sc1.w, sh1.w), 0.f);
    s0 += v0; m0 = fmaxf(m0, v0);
    s1 += v1; m1 = fmaxf(m1, v1);
    s2 += v2; m2 = fmaxf(m2, v2);
    s3 += v3; m3 = fmaxf(m3, v3);
    s4 += v4; m4 = fmaxf(m4, v4);
    s5 += v5; m5 = fmaxf(m5, v5);
    s6 += v6; m6 = fmaxf(m6, v6);
    s7 += v7; m7 = fmaxf(m7, v7);
  }
  redS[grp][c + 0] = s0; redM[grp][c + 0] = m0;
  redS[grp][c + 1] = s1; redM[grp][c + 1] = m1;
  redS[grp][c + 2] = s2; redM[grp][c + 2] = m2;
  redS[grp][c + 3] = s3; redM[grp][c + 3] = m3;
  redS[grp][c + 4] = s4; redM[grp][c + 4] = m4;
  redS[grp][c + 5] = s5; redM[grp][c + 5] = m5;
  redS[grp][c + 6] = s6; redM[grp][c + 6] = m6;
  redS[grp][c + 7] = s7; redM[grp][c + 7] = m7;
  __syncthreads();
  float s = 0.f, m = 0.f;
#pragma unroll
  for (int k = 0; k < 8; ++k) {
    s += redS[k][tid];
    m = fmaxf(m, redM[k][tid]);
  }
  float cnt = (float)(n1 - n0);
  pooled[g * 512 + tid] = s / fmaxf(cnt, 1.0f);
  pooled[g * 512 + 256 + tid] = m;
}

// ---------------- MLP + heads ----------------
__global__ __launch_bounds__(256) void k_mlp1(const float* __restrict__ P,
    const float* __restrict__ W, const float* __restrict__ b, float* __restrict__ O) {
  __shared__ float Ps[4 * 512];
  int tid = threadIdx.x;
  int g0 = blockIdx.x * 4;
  for (int j = 0; j < 8; ++j) Ps[j * 256 + tid] = P[g0 * 512 + j * 256 + tid];
  __syncthreads();
  float acc[4];
  float bb = b[tid];
#pragma unroll
  for (int gi = 0; gi < 4; ++gi) acc[gi] = bb;
  for (int k = 0; k < 512; ++k) {
    float w = W[k * 256 + tid];
#pragma unroll
    for (int gi = 0; gi < 4; ++gi) acc[gi] += Ps[gi * 512 + k] * w;
  }
#pragma unroll
  for (int gi = 0; gi < 4; ++gi)
    O[(g0 + gi) * 256 + tid] = fmaxf(acc[gi], 0.f);
}

__global__ __launch_bounds__(128) void k_mlp2(const float* __restrict__ S,
    const float* __restrict__ W, const float* __restrict__ b, float* __restrict__ O) {
  __shared__ float Ss[2 * 256];
  int tid = threadIdx.x;
  int g0 = blockIdx.x * 2;
  for (int j = 0; j < 4; ++j) Ss[j * 128 + tid] = S[g0 * 256 + j * 128 + tid];
  __syncthreads();
  float acc[2];
  float bb = b[tid];
  acc[0] = bb; acc[1] = bb;
  for (int k = 0; k < 256; ++k) {
    float w = W[k * 128 + tid];
    acc[0] += Ss[k] * w;
    acc[1] += Ss[256 + k] * w;
  }
  O[g0 * 128 + tid] = fmaxf(acc[0], 0.f);
  O[(g0 + 1) * 128 + tid] = fmaxf(acc[1], 0.f);
}

__global__ __launch_bounds__(128) void k_heads(const float* __restrict__ S,
    const float* __restrict__ hW1, const float* __restrict__ hb1,
    const float* __restrict__ hW2, const float* __restrict__ hb2,
    float* __restrict__ out) {
  __shared__ float ssm[128];
  __shared__ float t1[96];
  int g = blockIdx.x, tid = threadIdx.x;
  ssm[tid] = S[g * 128 + tid];
  __syncthreads();
  if (tid < 96) {
    int t = tid >> 5, o = tid & 31;
    float acc = hb1[t * 32 + o];
    for (int k = 0; k < 128; ++k) acc += ssm[k] * hW1[t * 4096 + k * 32 + o];
    t1[tid] = fmaxf(acc, 0.f);
  }
  __syncthreads();
  if (tid < 3) {
    float acc = hb2[tid];
    for (int o = 0; o < 32; ++o) acc += t1[tid * 32 + o] * hW2[tid * 32 + o];
    out[tid * NGRAPH + g] = acc;
  }
}

// ---------------- host launcher ----------------
extern "C" void kernel_launch(void* const* d_in, const int* in_sizes, int n_in,
                              void* d_out, int out_size, void* d_ws, size_t ws_size,
                              hipStream_t stream) {
  const float* x   = (const float*)d_in[0];
  const int* ei    = (const int*)d_in[1];
  const int* batch = (const int*)d_in[2];
  const float* W1 = (const float*)d_in[3];  const float* b1 = (const float*)d_in[4];
  const float* W2 = (const float*)d_in[5];  const float* b2 = (const float*)d_in[6];
  const float* W3 = (const float*)d_in[7];  const float* b3 = (const float*)d_in[8];
  const float* W4 = (const float*)d_in[9];  const float* b4 = (const float*)d_in[10];
  const float* g1 = (const float*)d_in[11]; const float* be1 = (const float*)d_in[12];
  const float* g2 = (const float*)d_in[13]; const float* be2 = (const float*)d_in[14];
  const float* g3 = (const float*)d_in[15]; const float* be3 = (const float*)d_in[16];
  const float* g4 = (const float*)d_in[17]; const float* be4 = (const float*)d_in[18];
  const float* sW1 = (const float*)d_in[19]; const float* sb1 = (const float*)d_in[20];
  const float* sW2 = (const float*)d_in[21]; const float* sb2 = (const float*)d_in[22];
  const float* hW1 = (const float*)d_in[23]; const float* hb1 = (const float*)d_in[24];
  const float* hW2 = (const float*)d_in[25]; const float* hb2 = (const float*)d_in[26];

  const int N = in_sizes[0] / 8;
  const int E = in_sizes[1] / 2;
  const int Npad = (N + 127) & ~127;
  const int* srcp = ei;
  const int* dstp = ei + E;

  char* base = (char*)d_ws;
  size_t off = 0;
  auto alloc = [&](size_t bytes) -> void* {
    void* p = base + off;
    off += (bytes + 255) & ~(size_t)255;
    return p;
  };
  unsigned short* Ybf = (unsigned short*)alloc((size_t)Npad * 256 * 2);
  unsigned short* Ahi = (unsigned short*)alloc((size_t)Npad * 256 * 2);
  float* dis  = (float*)alloc((size_t)N * 4);
  int* cnt    = (int*)alloc((size_t)N * 4);
  int* rs     = (int*)alloc((size_t)(N + 1) * 4);
  int* cursor = (int*)alloc((size_t)N * 4);
  int* es     = (int*)alloc((size_t)E * 4);
  int* bsum   = (int*)alloc(1024 * 4);
  int* bsumx  = (int*)alloc(1032 * 4);
  float* xa8  = (float*)alloc((size_t)N * 8 * 4);
  float* statsAll = (float*)alloc(2048 * 4);
  float* statsP   = (float*)alloc(12288 * 4);   // 3 layers x 8 slices x 512
  float* ssAll    = (float*)alloc(2048 * 4);
  unsigned short* Wblk = (unsigned short*)alloc(3 * 256 * 256 * 2);
  int* cntg    = (int*)alloc(2048 * 4);
  int* gstart  = (int*)alloc(2049 * 4);
  float* pooled = (float*)alloc((size_t)2048 * 512 * 4);
  float* s1b    = (float*)alloc((size_t)2048 * 256 * 4);
  float* s2b    = (float*)alloc((size_t)2048 * 128 * 4);
  int* cnts    = (int*)alloc(4 * 4);
  (void)ws_size; (void)n_in; (void)out_size;

  int nb = (N + TPB - 1) / TPB;
  int eb = (E + TPB - 1) / TPB;
  int nblocks1 = (N + 1023) / 1024;

  k_init<<<nb, TPB, 0, stream>>>(dis, cnt, cntg, statsAll, statsP, cnts, N);
  k_hist<<<eb, TPB, 0, stream>>>(dstp, dis, cnt, batch, cntg, E, N);
  k_scan1<<<nblocks1, 256, 0, stream>>>(cnt, rs, bsum, N);
  k_scan_small2<<<2, 256, 0, stream>>>(bsum, bsumx, nblocks1, cntg, gstart, NGRAPH);
  k_scan3<<<nb, TPB, 0, stream>>>(rs, bsumx, cursor, dis, N, E);
  k_scatter<<<eb, TPB, 0, stream>>>(srcp, dstp, cursor, es, E);

  // weight prep (layers 2..4) in one launch: K=64-blocked + swizzle-baked bf16
  k_wprep2<<<768, 256, 0, stream>>>(W2, W3, W4, Wblk);

  // ---- layer 1: aggregate on D=8, project (fp32), fused stats+scaleshift ----
  k_agg8<<<(N * 8 + TPB - 1) / TPB, TPB, 0, stream>>>(x, dis, rs, es, xa8, N);
  k_gemm8<<<(N + 63) / 64, 256, 0, stream>>>(xa8, W1, b1, Ybf, statsAll,
                                             g1, be1, ssAll, cnts + 0, N);

  // ---- layers 2..4 ----
  const float* bs_[3] = {b2, b3, b4};
  const float* gs[3]  = {g2, g3, g4};
  const float* bes[3] = {be2, be3, be4};
  for (int L = 0; L < 3; ++L) {
    k_agg_bn<<<(N + 7) / 8, 256, 0, stream>>>(Ybf, ssAll + L * 512, dis, rs, es,
                                              Ahi, N);
    k_gemm_mfma<<<(N + 63) / 64, 256, 0, stream>>>(Ahi, Wblk + L * 65536,
                                                   bs_[L], Ybf, statsP + L * 4096,
                                                   gs[L], bes[L],
                                                   ssAll + (L + 1) * 512,
                                                   cnts + 1 + L, N);
  }

  // ---- pooling (fused BN+ReLU of layer 4) + MLP + heads ----
  k_pool<<<NGRAPH, 256, 0, stream>>>(Ybf, ssAll + 3 * 512, gstart, pooled);
  k_mlp1<<<NGRAPH / 4, 256, 0, stream>>>(pooled, sW1, sb1, s1b);
  k_mlp2<<<NGRAPH / 2, 128, 0, stream>>>(s1b, sW2, sb2, s2b);
  k_heads<<<NGRAPH, 128, 0, stream>>>(s2b, hW1, hb1, hW2, hb2, (float*)d_out);
}

// Round 33
// 473.836 us; speedup vs baseline: 2.2666x; 2.2666x over previous
//
#include <hip/hip_runtime.h>
#include <math.h>

#define TPB 256
#define NGRAPH 2048

typedef __attribute__((ext_vector_type(8))) short bf16x8;
typedef __attribute__((ext_vector_type(4))) float f32x4;

__device__ __forceinline__ unsigned short f2bf(float f) {
  unsigned u = __float_as_uint(f);
  unsigned r = (u + 0x7FFF + ((u >> 16) & 1)) >> 16;
  return (unsigned short)r;
}
__device__ __forceinline__ float bf2f(unsigned short h) {
  return __uint_as_float(((unsigned)h) << 16);
}
__device__ __forceinline__ float bflo(unsigned u) {
  return __uint_as_float(u << 16);
}
__device__ __forceinline__ float bfhi(unsigned u) {
  return __uint_as_float(u & 0xFFFF0000u);
}

#define GLOAD_LDS16(G, L) \
  __builtin_amdgcn_global_load_lds((const __attribute__((address_space(1))) unsigned int*)(G), \
                                   (__attribute__((address_space(3))) unsigned int*)(L), 16, 0, 0)

// ---------------- init / degree / histograms ----------------
__global__ void k_init(float* __restrict__ deg, int* __restrict__ cnt,
                       int* __restrict__ cntg, float* __restrict__ statsAll,
                       float* __restrict__ statsP, int N) {
  int i = blockIdx.x * TPB + threadIdx.x;
  if (i < N) { deg[i] = 1.0f; cnt[i] = 0; }
  if (i < NGRAPH) cntg[i] = 0;
  if (i < 2048) statsAll[i] = 0.f;
  if (i < 12288) statsP[i] = 0.f;
}

// fused: edge-degree histogram (over E) + graph-size histogram (over N)
__global__ void k_hist(const int* __restrict__ dst, float* __restrict__ deg,
                       int* __restrict__ cnt, const int* __restrict__ batch,
                       int* __restrict__ cntg, int E, int N) {
  int i = blockIdx.x * TPB + threadIdx.x;
  if (i < E) {
    int d = dst[i];
    atomicAdd(&deg[d], 1.0f);
    atomicAdd(&cnt[d], 1);
  }
  if (i < N) atomicAdd(&cntg[batch[i]], 1);
}

// ---------------- scans ----------------
__global__ void k_scan1(const int* __restrict__ in, int* __restrict__ out,
                        int* __restrict__ bsum, int n) {
  __shared__ int ts[256];
  int tid = threadIdx.x;
  int base = blockIdx.x * 1024 + tid * 4;
  int v0 = (base + 0 < n) ? in[base + 0] : 0;
  int v1 = (base + 1 < n) ? in[base + 1] : 0;
  int v2 = (base + 2 < n) ? in[base + 2] : 0;
  int v3 = (base + 3 < n) ? in[base + 3] : 0;
  int s = v0 + v1 + v2 + v3;
  int run = s;
  ts[tid] = run; __syncthreads();
  for (int off = 1; off < 256; off <<= 1) {
    int add = (tid >= off) ? ts[tid - off] : 0;
    __syncthreads();
    run += add; ts[tid] = run; __syncthreads();
  }
  int acc = run - s;
  if (base + 0 < n) out[base + 0] = acc; acc += v0;
  if (base + 1 < n) out[base + 1] = acc; acc += v1;
  if (base + 2 < n) out[base + 2] = acc; acc += v2;
  if (base + 3 < n) out[base + 3] = acc;
  if (tid == 255) bsum[blockIdx.x] = run;
}

// dual single-block exclusive scan: block 0 scans (inA,nA)->dstA, block 1
// scans (inB,nB)->dstB. Both inputs are ready when this launches.
__global__ void k_scan_small2(const int* __restrict__ inA, int* __restrict__ dstA, int nA,
                              const int* __restrict__ inB, int* __restrict__ dstB, int nB) {
  __shared__ int ts[256];
  const int* in = (blockIdx.x == 0) ? inA : inB;
  int* dst      = (blockIdx.x == 0) ? dstA : dstB;
  int n         = (blockIdx.x == 0) ? nA : nB;
  int tid = threadIdx.x;
  int chunk = (n + 255) >> 8;
  int start = tid * chunk;
  int s = 0;
  for (int j = 0; j < chunk; ++j) { int idx = start + j; if (idx < n) s += in[idx]; }
  int run = s;
  ts[tid] = run; __syncthreads();
  for (int off = 1; off < 256; off <<= 1) {
    int add = (tid >= off) ? ts[tid - off] : 0;
    __syncthreads();
    run += add; ts[tid] = run; __syncthreads();
  }
  int acc = run - s;
  for (int j = 0; j < chunk; ++j) {
    int idx = start + j;
    if (idx < n) { dst[idx] = acc; acc += in[idx]; }
  }
  if (tid == 255) dst[n] = run;
}

// scan finalize + fused rsqrt(deg) -> dis (deg final since k_hist completed)
__global__ void k_scan3(int* __restrict__ rs, const int* __restrict__ bsumx,
                        int* __restrict__ cursor, float* __restrict__ dis,
                        int n, int total) {
  int i = blockIdx.x * TPB + threadIdx.x;
  if (i < n) {
    int v = rs[i] + bsumx[i >> 10];
    rs[i] = v; cursor[i] = v;
    dis[i] = rsqrtf(dis[i]);
  }
  if (i == 0) rs[n] = total;
}

__global__ void k_scatter(const int* __restrict__ src, const int* __restrict__ dst,
                          int* __restrict__ cursor, int* __restrict__ es, int E) {
  int e = blockIdx.x * TPB + threadIdx.x;
  if (e < E) {
    int d = dst[e];
    int p = atomicAdd(&cursor[d], 1);
    es[p] = src[e];
  }
}

// ------- weight prep: all 3 layers in one launch (grid 768) ----------------
// K=64-blocked transposed layout, swizzle pre-baked.
__global__ __launch_bounds__(256) void k_wprep2(const float* __restrict__ W2,
    const float* __restrict__ W3, const float* __restrict__ W4,
    unsigned short* __restrict__ Wblk) {
  int L = blockIdx.x >> 8;          // 0..2
  int c = blockIdx.x & 255;
  int k = threadIdx.x;
  const float* W = (L == 0) ? W2 : (L == 1) ? W3 : W4;
  float w = W[k * 256 + c];
  int t = k >> 6, kl = k & 63;
  Wblk[L * 65536 + t * 16384 + c * 64 + (kl ^ ((c & 7) << 3))] = f2bf(w);
}

// ---------------- layer-1 aggregation on D=8 (fp32) ----------------
__global__ void k_agg8(const float* __restrict__ x, const float* __restrict__ dis,
                       const int* __restrict__ rs, const int* __restrict__ es,
                       float* __restrict__ xa8, int N) {
  int t = blockIdx.x * TPB + threadIdx.x;
  int n = t >> 3, c = t & 7;
  if (n >= N) return;
  int e0 = rs[n], e1 = rs[n + 1];
  float acc = 0.f;
  for (int e = e0; e < e1; ++e) {
    int s = es[e];
    acc += dis[s] * x[s * 8 + c];
  }
  float dn = dis[n];
  xa8[n * 8 + c] = dn * acc + dn * dn * x[n * 8 + c];
}

// y[N,256] = xa8[N,8] @ W[8,256] + b, fused BN stats, bf16 output
__global__ __launch_bounds__(256) void k_gemm8(const float* __restrict__ A,
    const float* __restrict__ W, const float* __restrict__ b,
    unsigned short* __restrict__ Ybf, float* __restrict__ stats, int N) {
  __shared__ float Ws[8 * 256];
  __shared__ float bs[256];
  __shared__ float rows[64 * 8];
  int tid = threadIdx.x;
  int row0 = blockIdx.x * 64;
  for (int j = 0; j < 8; ++j) Ws[tid + j * 256] = W[tid + j * 256];
  bs[tid] = b[tid];
  int lim = N * 8;
  int o0 = row0 * 8 + tid, o1 = o0 + 256;
  rows[tid] = (o0 < lim) ? A[o0] : 0.f;
  rows[tid + 256] = (o1 < lim) ? A[o1] : 0.f;
  __syncthreads();
  float bb = bs[tid];
  float s = 0.f, s2 = 0.f;
  for (int r = 0; r < 64; r += 2) {
    int rowA = row0 + r, rowB = rowA + 1;
    float a0 = bb, a1 = bb;
#pragma unroll
    for (int k = 0; k < 8; ++k) {
      a0 = fmaf(rows[r * 8 + k], Ws[k * 256 + tid], a0);
      a1 = fmaf(rows[r * 8 + 8 + k], Ws[k * 256 + tid], a1);
    }
    if (rowA < N) {
      Ybf[(size_t)rowA * 256 + tid] = f2bf(a0);
      s += a0; s2 += a0 * a0;
    }
    if (rowB < N) {
      Ybf[(size_t)rowB * 256 + tid] = f2bf(a1);
      s += a1; s2 += a1 * a1;
    }
  }
  atomicAdd(&stats[tid], s);
  atomicAdd(&stats[256 + tid], s2);
}

// ------- fused BN+ReLU aggregation, half-wave per node (r22-measured) ------
__global__ __launch_bounds__(256) void k_agg_bn(const unsigned short* __restrict__ Ybf,
    const float* __restrict__ ss, const float* __restrict__ dis,
    const int* __restrict__ rs, const int* __restrict__ es,
    unsigned short* __restrict__ Ahi, int N) {
  int l32 = threadIdx.x & 31;
  int n = blockIdx.x * 8 + (threadIdx.x >> 5);
  if (n >= N) return;
  int c = l32 * 8;
  float4 sc0 = *(const float4*)&ss[c];
  float4 sc1 = *(const float4*)&ss[c + 4];
  float4 sh0 = *(const float4*)&ss[256 + c];
  float4 sh1 = *(const float4*)&ss[256 + c + 4];
  int e0 = rs[n], e1 = rs[n + 1];
  float a0 = 0.f, a1 = 0.f, a2 = 0.f, a3 = 0.f;
  float a4 = 0.f, a5 = 0.f, a6 = 0.f, a7 = 0.f;
#define BNR8(Q, d)                                                           \
  {                                                                          \
    a0 += (d) * fmaxf(fmaf(bflo(Q.x), sc0.x, sh0.x), 0.f);                   \
    a1 += (d) * fmaxf(fmaf(bfhi(Q.x), sc0.y, sh0.y), 0.f);                   \
    a2 += (d) * fmaxf(fmaf(bflo(Q.y), sc0.z, sh0.z), 0.f);                   \
    a3 += (d) * fmaxf(fmaf(bfhi(Q.y), sc0.w, sh0.w), 0.f);                   \
    a4 += (d) * fmaxf(fmaf(bflo(Q.z), sc1.x, sh1.x), 0.f);                   \
    a5 += (d) * fmaxf(fmaf(bfhi(Q.z), sc1.y, sh1.y), 0.f);                   \
    a6 += (d) * fmaxf(fmaf(bflo(Q.w), sc1.z, sh1.z), 0.f);                   \
    a7 += (d) * fmaxf(fmaf(bfhi(Q.w), sc1.w, sh1.w), 0.f);                   \
  }
  int e = e0;
  for (; e + 2 <= e1; e += 2) {
    int s0 = es[e], s1 = es[e + 1];
    float d0 = dis[s0], d1 = dis[s1];
    uint4 y0 = *(const uint4*)&Ybf[(size_t)s0 * 256 + c];
    uint4 y1 = *(const uint4*)&Ybf[(size_t)s1 * 256 + c];
    BNR8(y0, d0);
    BNR8(y1, d1);
  }
  if (e < e1) {
    int s0 = es[e];
    float d0 = dis[s0];
    uint4 y0 = *(const uint4*)&Ybf[(size_t)s0 * 256 + c];
    BNR8(y0, d0);
  }
#undef BNR8
  float dn = dis[n];
  float dn2 = dn * dn;
  uint4 yb = *(const uint4*)&Ybf[(size_t)n * 256 + c];
  float r0 = dn * a0 + dn2 * fmaxf(fmaf(bflo(yb.x), sc0.x, sh0.x), 0.f);
  float r1 = dn * a1 + dn2 * fmaxf(fmaf(bfhi(yb.x), sc0.y, sh0.y), 0.f);
  float r2 = dn * a2 + dn2 * fmaxf(fmaf(bflo(yb.y), sc0.z, sh0.z), 0.f);
  float r3 = dn * a3 + dn2 * fmaxf(fmaf(bfhi(yb.y), sc0.w, sh0.w), 0.f);
  float r4 = dn * a4 + dn2 * fmaxf(fmaf(bflo(yb.z), sc1.x, sh1.x), 0.f);
  float r5 = dn * a5 + dn2 * fmaxf(fmaf(bfhi(yb.z), sc1.y, sh1.y), 0.f);
  float r6 = dn * a6 + dn2 * fmaxf(fmaf(bflo(yb.w), sc1.z, sh1.z), 0.f);
  float r7 = dn * a7 + dn2 * fmaxf(fmaf(bfhi(yb.w), sc1.w, sh1.w), 0.f);
  uint4 o;
  o.x = (unsigned)f2bf(r0) | ((unsigned)f2bf(r1) << 16);
  o.y = (unsigned)f2bf(r2) | ((unsigned)f2bf(r3) << 16);
  o.z = (unsigned)f2bf(r4) | ((unsigned)f2bf(r5) << 16);
  o.w = (unsigned)f2bf(r6) | ((unsigned)f2bf(r7) << 16);
  *(uint4*)&Ahi[(size_t)n * 256 + c] = o;
}

// ---------------- MFMA GEMM (r20/r26-measured best: ~55us @29% occ) -------
__global__ __launch_bounds__(256) void k_gemm_mfma(
    const unsigned short* __restrict__ A,
    const unsigned short* __restrict__ Wblk,
    const float* __restrict__ bias, unsigned short* __restrict__ Ybf,
    float* __restrict__ statsP, int M) {
  __shared__ unsigned short Wlds[16384];  // 32KB W slab / epilogue stage
  __shared__ float bstats[512];
  const int tid = threadIdx.x;
  const int lane = tid & 63;
  const int w = tid >> 6;
  const int l15 = lane & 15, lg = lane >> 4;
  const int r0 = blockIdx.x * 64 + w * 16;

  bstats[tid] = 0.f;
  bstats[tid + 256] = 0.f;

  const unsigned short* Ap = A + (size_t)(r0 + l15) * 256 + lg * 8;

  f32x4 acc[16] = {};
#pragma unroll
  for (int t = 0; t < 4; ++t) {
#pragma unroll
    for (int it = 0; it < 8; ++it)
      GLOAD_LDS16(Wblk + t * 16384 + it * 2048 + tid * 8,
                  &Wlds[it * 2048 + tid * 8]);
    bf16x8 a0 = *(const bf16x8*)(Ap + t * 64);
    bf16x8 a1 = *(const bf16x8*)(Ap + t * 64 + 32);
    asm volatile("s_waitcnt vmcnt(0)" ::: "memory");
    __builtin_amdgcn_s_barrier();
#pragma unroll
    for (int kk2 = 0; kk2 < 2; ++kk2) {
      bf16x8 a = kk2 ? a1 : a0;
#pragma unroll
      for (int n = 0; n < 16; ++n) {
        int c = n * 16 + l15;
        bf16x8 b = *(const bf16x8*)&Wlds[c * 64 +
                     ((kk2 * 32 + lg * 8) ^ ((l15 & 7) << 3))];
        acc[n] = __builtin_amdgcn_mfma_f32_16x16x32_bf16(a, b, acc[n], 0, 0, 0);
      }
    }
    asm volatile("s_waitcnt lgkmcnt(0)" ::: "memory");
    __builtin_amdgcn_s_barrier();
  }

  unsigned short* stage = Wlds;  // 64 rows x 256 cols bf16 = 32KB
#pragma unroll
  for (int n = 0; n < 16; ++n) {
    int col = n * 16 + l15;
    float bv = bias[col];
    float s = 0.f, s2 = 0.f;
    f32x4 v = acc[n];
#pragma unroll
    for (int j = 0; j < 4; ++j) {
      float val = v[j] + bv;
      int rl = w * 16 + lg * 4 + j;
      stage[rl * 256 + col] = f2bf(val);
      if (blockIdx.x * 64 + rl < M) { s += val; s2 += val * val; }
    }
    s += __shfl_xor(s, 16);  s += __shfl_xor(s, 32);
    s2 += __shfl_xor(s2, 16); s2 += __shfl_xor(s2, 32);
    if (lg == 0) {
      atomicAdd(&bstats[col], s);
      atomicAdd(&bstats[256 + col], s2);
    }
  }
  __syncthreads();
#pragma unroll
  for (int it = 0; it < 8; ++it) {
    int idx = it * 256 + tid;
    int rl = idx >> 5;
    int c16 = idx & 31;
    int grow = blockIdx.x * 64 + rl;
    if (grow < M)
      *(int4*)((char*)Ybf + (size_t)grow * 512 + c16 * 16) =
          *(const int4*)((const char*)stage + rl * 512 + c16 * 16);
  }
  float* sp = statsP + (blockIdx.x & 7) * 512;
  atomicAdd(&sp[tid], bstats[tid]);
  atomicAdd(&sp[256 + tid], bstats[256 + tid]);
}

// ---------------- BN scale/shift (sums npart partial slices) ----------------
__global__ void k_scaleshift(const float* __restrict__ base, int npart,
                             const float* __restrict__ g,
                             const float* __restrict__ be, float* __restrict__ ss, int N) {
  int c = threadIdx.x;
  float s = 0.f, s2 = 0.f;
  for (int p = 0; p < npart; ++p) {
    s += base[p * 512 + c];
    s2 += base[p * 512 + 256 + c];
  }
  float inv = 1.0f / (float)N;
  float mean = s * inv;
  float var = s2 * inv - mean * mean;
  var = fmaxf(var, 0.f);
  float sc = g[c] * rsqrtf(var + 1e-5f);
  ss[c] = sc;
  ss[256 + c] = be[c] - mean * sc;
}

// ---------------- pooling with fused BN+ReLU, vectorized (r29-measured) -----
__global__ __launch_bounds__(256) void k_pool(const unsigned short* __restrict__ Ybf,
    const float* __restrict__ ss, const int* __restrict__ gstart,
    float* __restrict__ pooled) {
  __shared__ float redS[8][256];
  __shared__ float redM[8][256];
  int g = blockIdx.x;
  int tid = threadIdx.x;
  int grp = tid >> 5;      // 0..7 row-group
  int l32 = tid & 31;
  int c = l32 * 8;
  float4 sc0 = *(const float4*)&ss[c];
  float4 sc1 = *(const float4*)&ss[c + 4];
  float4 sh0 = *(const float4*)&ss[256 + c];
  float4 sh1 = *(const float4*)&ss[256 + c + 4];
  int n0 = gstart[g], n1 = gstart[g + 1];
  float s0 = 0.f, s1 = 0.f, s2 = 0.f, s3 = 0.f, s4 = 0.f, s5 = 0.f, s6 = 0.f, s7 = 0.f;
  float m0 = 0.f, m1 = 0.f, m2 = 0.f, m3 = 0.f, m4 = 0.f, m5 = 0.f, m6 = 0.f, m7 = 0.f;
  for (int n = n0 + grp; n < n1; n += 8) {
    uint4 y = *(const uint4*)&Ybf[(size_t)n * 256 + c];
    float v0 = fmaxf(fmaf(bflo(y.x), sc0.x, sh0.x), 0.f);
    float v1 = fmaxf(fmaf(bfhi(y.x), sc0.y, sh0.y), 0.f);
    float v2 = fmaxf(fmaf(bflo(y.y), sc0.z, sh0.z), 0.f);
    float v3 = fmaxf(fmaf(bfhi(y.y), sc0.w, sh0.w), 0.f);
    float v4 = fmaxf(fmaf(bflo(y.z), sc1.x, sh1.x), 0.f);
    float v5 = fmaxf(fmaf(bfhi(y.z), sc1.y, sh1.y), 0.f);
    float v6 = fmaxf(fmaf(bflo(y.w), sc1.z, sh1.z), 0.f);
    float v7 = fmaxf(fmaf(bfhi(y.w), sc1.w, sh1.w), 0.f);
    s0 += v0; m0 = fmaxf(m0, v0);
    s1 += v1; m1 = fmaxf(m1, v1);
    s2 += v2; m2 = fmaxf(m2, v2);
    s3 += v3; m3 = fmaxf(m3, v3);
    s4 += v4; m4 = fmaxf(m4, v4);
    s5 += v5; m5 = fmaxf(m5, v5);
    s6 += v6; m6 = fmaxf(m6, v6);
    s7 += v7; m7 = fmaxf(m7, v7);
  }
  redS[grp][c + 0] = s0; redM[grp][c + 0] = m0;
  redS[grp][c + 1] = s1; redM[grp][c + 1] = m1;
  redS[grp][c + 2] = s2; redM[grp][c + 2] = m2;
  redS[grp][c + 3] = s3; redM[grp][c + 3] = m3;
  redS[grp][c + 4] = s4; redM[grp][c + 4] = m4;
  redS[grp][c + 5] = s5; redM[grp][c + 5] = m5;
  redS[grp][c + 6] = s6; redM[grp][c + 6] = m6;
  redS[grp][c + 7] = s7; redM[grp][c + 7] = m7;
  __syncthreads();
  float s = 0.f, m = 0.f;
#pragma unroll
  for (int k = 0; k < 8; ++k) {
    s += redS[k][tid];
    m = fmaxf(m, redM[k][tid]);
  }
  float cnt = (float)(n1 - n0);
  pooled[g * 512 + tid] = s / fmaxf(cnt, 1.0f);
  pooled[g * 512 + 256 + tid] = m;
}

// ---------------- MLP + heads ----------------
__global__ __launch_bounds__(256) void k_mlp1(const float* __restrict__ P,
    const float* __restrict__ W, const float* __restrict__ b, float* __restrict__ O) {
  __shared__ float Ps[4 * 512];
  int tid = threadIdx.x;
  int g0 = blockIdx.x * 4;
  for (int j = 0; j < 8; ++j) Ps[j * 256 + tid] = P[g0 * 512 + j * 256 + tid];
  __syncthreads();
  float acc[4];
  float bb = b[tid];
#pragma unroll
  for (int gi = 0; gi < 4; ++gi) acc[gi] = bb;
  for (int k = 0; k < 512; ++k) {
    float w = W[k * 256 + tid];
#pragma unroll
    for (int gi = 0; gi < 4; ++gi) acc[gi] += Ps[gi * 512 + k] * w;
  }
#pragma unroll
  for (int gi = 0; gi < 4; ++gi)
    O[(g0 + gi) * 256 + tid] = fmaxf(acc[gi], 0.f);
}

__global__ __launch_bounds__(128) void k_mlp2(const float* __restrict__ S,
    const float* __restrict__ W, const float* __restrict__ b, float* __restrict__ O) {
  __shared__ float Ss[2 * 256];
  int tid = threadIdx.x;
  int g0 = blockIdx.x * 2;
  for (int j = 0; j < 4; ++j) Ss[j * 128 + tid] = S[g0 * 256 + j * 128 + tid];
  __syncthreads();
  float acc[2];
  float bb = b[tid];
  acc[0] = bb; acc[1] = bb;
  for (int k = 0; k < 256; ++k) {
    float w = W[k * 128 + tid];
    acc[0] += Ss[k] * w;
    acc[1] += Ss[256 + k] * w;
  }
  O[g0 * 128 + tid] = fmaxf(acc[0], 0.f);
  O[(g0 + 1) * 128 + tid] = fmaxf(acc[1], 0.f);
}

__global__ __launch_bounds__(128) void k_heads(const float* __restrict__ S,
    const float* __restrict__ hW1, const float* __restrict__ hb1,
    const float* __restrict__ hW2, const float* __restrict__ hb2,
    float* __restrict__ out) {
  __shared__ float ssm[128];
  __shared__ float t1[96];
  int g = blockIdx.x, tid = threadIdx.x;
  ssm[tid] = S[g * 128 + tid];
  __syncthreads();
  if (tid < 96) {
    int t = tid >> 5, o = tid & 31;
    float acc = hb1[t * 32 + o];
    for (int k = 0; k < 128; ++k) acc += ssm[k] * hW1[t * 4096 + k * 32 + o];
    t1[tid] = fmaxf(acc, 0.f);
  }
  __syncthreads();
  if (tid < 3) {
    float acc = hb2[tid];
    for (int o = 0; o < 32; ++o) acc += t1[tid * 32 + o] * hW2[tid * 32 + o];
    out[tid * NGRAPH + g] = acc;
  }
}

// ---------------- host launcher ----------------
extern "C" void kernel_launch(void* const* d_in, const int* in_sizes, int n_in,
                              void* d_out, int out_size, void* d_ws, size_t ws_size,
                              hipStream_t stream) {
  const float* x   = (const float*)d_in[0];
  const int* ei    = (const int*)d_in[1];
  const int* batch = (const int*)d_in[2];
  const float* W1 = (const float*)d_in[3];  const float* b1 = (const float*)d_in[4];
  const float* W2 = (const float*)d_in[5];  const float* b2 = (const float*)d_in[6];
  const float* W3 = (const float*)d_in[7];  const float* b3 = (const float*)d_in[8];
  const float* W4 = (const float*)d_in[9];  const float* b4 = (const float*)d_in[10];
  const float* g1 = (const float*)d_in[11]; const float* be1 = (const float*)d_in[12];
  const float* g2 = (const float*)d_in[13]; const float* be2 = (const float*)d_in[14];
  const float* g3 = (const float*)d_in[15]; const float* be3 = (const float*)d_in[16];
  const float* g4 = (const float*)d_in[17]; const float* be4 = (const float*)d_in[18];
  const float* sW1 = (const float*)d_in[19]; const float* sb1 = (const float*)d_in[20];
  const float* sW2 = (const float*)d_in[21]; const float* sb2 = (const float*)d_in[22];
  const float* hW1 = (const float*)d_in[23]; const float* hb1 = (const float*)d_in[24];
  const float* hW2 = (const float*)d_in[25]; const float* hb2 = (const float*)d_in[26];

  const int N = in_sizes[0] / 8;
  const int E = in_sizes[1] / 2;
  const int Npad = (N + 127) & ~127;
  const int* srcp = ei;
  const int* dstp = ei + E;

  char* base = (char*)d_ws;
  size_t off = 0;
  auto alloc = [&](size_t bytes) -> void* {
    void* p = base + off;
    off += (bytes + 255) & ~(size_t)255;
    return p;
  };
  unsigned short* Ybf = (unsigned short*)alloc((size_t)Npad * 256 * 2);
  unsigned short* Ahi = (unsigned short*)alloc((size_t)Npad * 256 * 2);
  float* dis  = (float*)alloc((size_t)N * 4);
  int* cnt    = (int*)alloc((size_t)N * 4);
  int* rs     = (int*)alloc((size_t)(N + 1) * 4);
  int* cursor = (int*)alloc((size_t)N * 4);
  int* es     = (int*)alloc((size_t)E * 4);
  int* bsum   = (int*)alloc(1024 * 4);
  int* bsumx  = (int*)alloc(1032 * 4);
  float* xa8  = (float*)alloc((size_t)N * 8 * 4);
  float* statsAll = (float*)alloc(2048 * 4);
  float* statsP   = (float*)alloc(12288 * 4);   // 3 layers x 8 slices x 512
  float* ssAll    = (float*)alloc(2048 * 4);
  unsigned short* Wblk = (unsigned short*)alloc(3 * 256 * 256 * 2);
  int* cntg    = (int*)alloc(2048 * 4);
  int* gstart  = (int*)alloc(2049 * 4);
  float* pooled = (float*)alloc((size_t)2048 * 512 * 4);
  float* s1b    = (float*)alloc((size_t)2048 * 256 * 4);
  float* s2b    = (float*)alloc((size_t)2048 * 128 * 4);
  (void)ws_size; (void)n_in; (void)out_size;

  int nb = (N + TPB - 1) / TPB;
  int eb = (E + TPB - 1) / TPB;
  int nblocks1 = (N + 1023) / 1024;

  k_init<<<nb, TPB, 0, stream>>>(dis, cnt, cntg, statsAll, statsP, N);
  k_hist<<<eb, TPB, 0, stream>>>(dstp, dis, cnt, batch, cntg, E, N);
  k_scan1<<<nblocks1, 256, 0, stream>>>(cnt, rs, bsum, N);
  k_scan_small2<<<2, 256, 0, stream>>>(bsum, bsumx, nblocks1, cntg, gstart, NGRAPH);
  k_scan3<<<nb, TPB, 0, stream>>>(rs, bsumx, cursor, dis, N, E);
  k_scatter<<<eb, TPB, 0, stream>>>(srcp, dstp, cursor, es, E);

  // weight prep (layers 2..4) in one launch: K=64-blocked + swizzle-baked bf16
  k_wprep2<<<768, 256, 0, stream>>>(W2, W3, W4, Wblk);

  // ---- layer 1: aggregate on D=8, project (fp32), fused stats ----
  k_agg8<<<(N * 8 + TPB - 1) / TPB, TPB, 0, stream>>>(x, dis, rs, es, xa8, N);
  k_gemm8<<<(N + 63) / 64, 256, 0, stream>>>(xa8, W1, b1, Ybf, statsAll, N);
  k_scaleshift<<<1, 256, 0, stream>>>(statsAll, 1, g1, be1, ssAll, N);

  // ---- layers 2..4 ----
  const float* bs_[3] = {b2, b3, b4};
  const float* gs[3]  = {g2, g3, g4};
  const float* bes[3] = {be2, be3, be4};
  for (int L = 0; L < 3; ++L) {
    k_agg_bn<<<(N + 7) / 8, 256, 0, stream>>>(Ybf, ssAll + L * 512, dis, rs, es,
                                              Ahi, N);
    k_gemm_mfma<<<(N + 63) / 64, 256, 0, stream>>>(Ahi, Wblk + L * 65536,
                                                   bs_[L], Ybf, statsP + L * 4096, N);
    k_scaleshift<<<1, 256, 0, stream>>>(statsP + L * 4096, 8, gs[L], bes[L],
                                        ssAll + (L + 1) * 512, N);
  }

  // ---- pooling (fused BN+ReLU of layer 4) + MLP + heads ----
  k_pool<<<NGRAPH, 256, 0, stream>>>(Ybf, ssAll + 3 * 512, gstart, pooled);
  k_mlp1<<<NGRAPH / 4, 256, 0, stream>>>(pooled, sW1, sb1, s1b);
  k_mlp2<<<NGRAPH / 2, 128, 0, stream>>>(s1b, sW2, sb2, s2b);
  k_heads<<<NGRAPH, 128, 0, stream>>>(s2b, hW1, hb1, hW2, hb2, (float*)d_out);
}

// Round 34
// 470.850 us; speedup vs baseline: 2.2810x; 1.0063x over previous
//
#include <hip/hip_runtime.h>
#include <math.h>

#define TPB 256
#define NGRAPH 2048

typedef __attribute__((ext_vector_type(8))) short bf16x8;
typedef __attribute__((ext_vector_type(4))) float f32x4;

__device__ __forceinline__ unsigned short f2bf(float f) {
  unsigned u = __float_as_uint(f);
  unsigned r = (u + 0x7FFF + ((u >> 16) & 1)) >> 16;
  return (unsigned short)r;
}
__device__ __forceinline__ float bf2f(unsigned short h) {
  return __uint_as_float(((unsigned)h) << 16);
}
__device__ __forceinline__ float bflo(unsigned u) {
  return __uint_as_float(u << 16);
}
__device__ __forceinline__ float bfhi(unsigned u) {
  return __uint_as_float(u & 0xFFFF0000u);
}

#define GLOAD_LDS16(G, L) \
  __builtin_amdgcn_global_load_lds((const __attribute__((address_space(1))) unsigned int*)(G), \
                                   (__attribute__((address_space(3))) unsigned int*)(L), 16, 0, 0)

// ---------------- init / degree / histograms ----------------
__global__ void k_init(float* __restrict__ deg, int* __restrict__ cnt,
                       int* __restrict__ cntg, float* __restrict__ statsAll,
                       float* __restrict__ statsP, int N) {
  int i = blockIdx.x * TPB + threadIdx.x;
  if (i < N) { deg[i] = 1.0f; cnt[i] = 0; }
  if (i < NGRAPH) cntg[i] = 0;
  if (i < 2048) statsAll[i] = 0.f;
  if (i < 12288) statsP[i] = 0.f;
}

// fused: edge-degree histogram (over E) + graph-size histogram (over N)
__global__ void k_hist(const int* __restrict__ dst, float* __restrict__ deg,
                       int* __restrict__ cnt, const int* __restrict__ batch,
                       int* __restrict__ cntg, int E, int N) {
  int i = blockIdx.x * TPB + threadIdx.x;
  if (i < E) {
    int d = dst[i];
    atomicAdd(&deg[d], 1.0f);
    atomicAdd(&cnt[d], 1);
  }
  if (i < N) atomicAdd(&cntg[batch[i]], 1);
}

// ---------------- scans ----------------
__global__ void k_scan1(const int* __restrict__ in, int* __restrict__ out,
                        int* __restrict__ bsum, int n) {
  __shared__ int ts[256];
  int tid = threadIdx.x;
  int base = blockIdx.x * 1024 + tid * 4;
  int v0 = (base + 0 < n) ? in[base + 0] : 0;
  int v1 = (base + 1 < n) ? in[base + 1] : 0;
  int v2 = (base + 2 < n) ? in[base + 2] : 0;
  int v3 = (base + 3 < n) ? in[base + 3] : 0;
  int s = v0 + v1 + v2 + v3;
  int run = s;
  ts[tid] = run; __syncthreads();
  for (int off = 1; off < 256; off <<= 1) {
    int add = (tid >= off) ? ts[tid - off] : 0;
    __syncthreads();
    run += add; ts[tid] = run; __syncthreads();
  }
  int acc = run - s;
  if (base + 0 < n) out[base + 0] = acc; acc += v0;
  if (base + 1 < n) out[base + 1] = acc; acc += v1;
  if (base + 2 < n) out[base + 2] = acc; acc += v2;
  if (base + 3 < n) out[base + 3] = acc;
  if (tid == 255) bsum[blockIdx.x] = run;
}

// dual single-block exclusive scan: block 0 scans (inA,nA)->dstA, block 1
// scans (inB,nB)->dstB. Both inputs are ready when this launches.
__global__ void k_scan_small2(const int* __restrict__ inA, int* __restrict__ dstA, int nA,
                              const int* __restrict__ inB, int* __restrict__ dstB, int nB) {
  __shared__ int ts[256];
  const int* in = (blockIdx.x == 0) ? inA : inB;
  int* dst      = (blockIdx.x == 0) ? dstA : dstB;
  int n         = (blockIdx.x == 0) ? nA : nB;
  int tid = threadIdx.x;
  int chunk = (n + 255) >> 8;
  int start = tid * chunk;
  int s = 0;
  for (int j = 0; j < chunk; ++j) { int idx = start + j; if (idx < n) s += in[idx]; }
  int run = s;
  ts[tid] = run; __syncthreads();
  for (int off = 1; off < 256; off <<= 1) {
    int add = (tid >= off) ? ts[tid - off] : 0;
    __syncthreads();
    run += add; ts[tid] = run; __syncthreads();
  }
  int acc = run - s;
  for (int j = 0; j < chunk; ++j) {
    int idx = start + j;
    if (idx < n) { dst[idx] = acc; acc += in[idx]; }
  }
  if (tid == 255) dst[n] = run;
}

// scan finalize + fused rsqrt(deg) -> dis (deg final since k_hist completed)
__global__ void k_scan3(int* __restrict__ rs, const int* __restrict__ bsumx,
                        int* __restrict__ cursor, float* __restrict__ dis,
                        int n, int total) {
  int i = blockIdx.x * TPB + threadIdx.x;
  if (i < n) {
    int v = rs[i] + bsumx[i >> 10];
    rs[i] = v; cursor[i] = v;
    dis[i] = rsqrtf(dis[i]);
  }
  if (i == 0) rs[n] = total;
}

__global__ void k_scatter(const int* __restrict__ src, const int* __restrict__ dst,
                          int* __restrict__ cursor, int* __restrict__ es, int E) {
  int e = blockIdx.x * TPB + threadIdx.x;
  if (e < E) {
    int d = dst[e];
    int p = atomicAdd(&cursor[d], 1);
    es[p] = src[e];
  }
}

// ------- weight prep: all 3 layers in one launch (grid 768) ----------------
// K=64-blocked transposed layout, swizzle pre-baked.
__global__ __launch_bounds__(256) void k_wprep2(const float* __restrict__ W2,
    const float* __restrict__ W3, const float* __restrict__ W4,
    unsigned short* __restrict__ Wblk) {
  int L = blockIdx.x >> 8;          // 0..2
  int c = blockIdx.x & 255;
  int k = threadIdx.x;
  const float* W = (L == 0) ? W2 : (L == 1) ? W3 : W4;
  float w = W[k * 256 + c];
  int t = k >> 6, kl = k & 63;
  Wblk[L * 65536 + t * 16384 + c * 64 + (kl ^ ((c & 7) << 3))] = f2bf(w);
}

// ---------------- layer-1 aggregation on D=8 (fp32) ----------------
__global__ void k_agg8(const float* __restrict__ x, const float* __restrict__ dis,
                       const int* __restrict__ rs, const int* __restrict__ es,
                       float* __restrict__ xa8, int N) {
  int t = blockIdx.x * TPB + threadIdx.x;
  int n = t >> 3, c = t & 7;
  if (n >= N) return;
  int e0 = rs[n], e1 = rs[n + 1];
  float acc = 0.f;
  for (int e = e0; e < e1; ++e) {
    int s = es[e];
    acc += dis[s] * x[s * 8 + c];
  }
  float dn = dis[n];
  xa8[n * 8 + c] = dn * acc + dn * dn * x[n * 8 + c];
}

// y[N,256] = xa8[N,8] @ W[8,256] + b, fused BN stats, bf16 output
__global__ __launch_bounds__(256) void k_gemm8(const float* __restrict__ A,
    const float* __restrict__ W, const float* __restrict__ b,
    unsigned short* __restrict__ Ybf, float* __restrict__ stats, int N) {
  __shared__ float Ws[8 * 256];
  __shared__ float bs[256];
  __shared__ float rows[64 * 8];
  int tid = threadIdx.x;
  int row0 = blockIdx.x * 64;
  for (int j = 0; j < 8; ++j) Ws[tid + j * 256] = W[tid + j * 256];
  bs[tid] = b[tid];
  int lim = N * 8;
  int o0 = row0 * 8 + tid, o1 = o0 + 256;
  rows[tid] = (o0 < lim) ? A[o0] : 0.f;
  rows[tid + 256] = (o1 < lim) ? A[o1] : 0.f;
  __syncthreads();
  float bb = bs[tid];
  float s = 0.f, s2 = 0.f;
  for (int r = 0; r < 64; r += 2) {
    int rowA = row0 + r, rowB = rowA + 1;
    float a0 = bb, a1 = bb;
#pragma unroll
    for (int k = 0; k < 8; ++k) {
      a0 = fmaf(rows[r * 8 + k], Ws[k * 256 + tid], a0);
      a1 = fmaf(rows[r * 8 + 8 + k], Ws[k * 256 + tid], a1);
    }
    if (rowA < N) {
      Ybf[(size_t)rowA * 256 + tid] = f2bf(a0);
      s += a0; s2 += a0 * a0;
    }
    if (rowB < N) {
      Ybf[(size_t)rowB * 256 + tid] = f2bf(a1);
      s += a1; s2 += a1 * a1;
    }
  }
  atomicAdd(&stats[tid], s);
  atomicAdd(&stats[256 + tid], s2);
}

// ------- fused BN+ReLU aggregation, half-wave per node (r22-measured) ------
__global__ __launch_bounds__(256) void k_agg_bn(const unsigned short* __restrict__ Ybf,
    const float* __restrict__ ss, const float* __restrict__ dis,
    const int* __restrict__ rs, const int* __restrict__ es,
    unsigned short* __restrict__ Ahi, int N) {
  int l32 = threadIdx.x & 31;
  int n = blockIdx.x * 8 + (threadIdx.x >> 5);
  if (n >= N) return;
  int c = l32 * 8;
  float4 sc0 = *(const float4*)&ss[c];
  float4 sc1 = *(const float4*)&ss[c + 4];
  float4 sh0 = *(const float4*)&ss[256 + c];
  float4 sh1 = *(const float4*)&ss[256 + c + 4];
  int e0 = rs[n], e1 = rs[n + 1];
  float a0 = 0.f, a1 = 0.f, a2 = 0.f, a3 = 0.f;
  float a4 = 0.f, a5 = 0.f, a6 = 0.f, a7 = 0.f;
#define BNR8(Q, d)                                                           \
  {                                                                          \
    a0 += (d) * fmaxf(fmaf(bflo(Q.x), sc0.x, sh0.x), 0.f);                   \
    a1 += (d) * fmaxf(fmaf(bfhi(Q.x), sc0.y, sh0.y), 0.f);                   \
    a2 += (d) * fmaxf(fmaf(bflo(Q.y), sc0.z, sh0.z), 0.f);                   \
    a3 += (d) * fmaxf(fmaf(bfhi(Q.y), sc0.w, sh0.w), 0.f);                   \
    a4 += (d) * fmaxf(fmaf(bflo(Q.z), sc1.x, sh1.x), 0.f);                   \
    a5 += (d) * fmaxf(fmaf(bfhi(Q.z), sc1.y, sh1.y), 0.f);                   \
    a6 += (d) * fmaxf(fmaf(bflo(Q.w), sc1.z, sh1.z), 0.f);                   \
    a7 += (d) * fmaxf(fmaf(bfhi(Q.w), sc1.w, sh1.w), 0.f);                   \
  }
  int e = e0;
  for (; e + 2 <= e1; e += 2) {
    int s0 = es[e], s1 = es[e + 1];
    float d0 = dis[s0], d1 = dis[s1];
    uint4 y0 = *(const uint4*)&Ybf[(size_t)s0 * 256 + c];
    uint4 y1 = *(const uint4*)&Ybf[(size_t)s1 * 256 + c];
    BNR8(y0, d0);
    BNR8(y1, d1);
  }
  if (e < e1) {
    int s0 = es[e];
    float d0 = dis[s0];
    uint4 y0 = *(const uint4*)&Ybf[(size_t)s0 * 256 + c];
    BNR8(y0, d0);
  }
#undef BNR8
  float dn = dis[n];
  float dn2 = dn * dn;
  uint4 yb = *(const uint4*)&Ybf[(size_t)n * 256 + c];
  float r0 = dn * a0 + dn2 * fmaxf(fmaf(bflo(yb.x), sc0.x, sh0.x), 0.f);
  float r1 = dn * a1 + dn2 * fmaxf(fmaf(bfhi(yb.x), sc0.y, sh0.y), 0.f);
  float r2 = dn * a2 + dn2 * fmaxf(fmaf(bflo(yb.y), sc0.z, sh0.z), 0.f);
  float r3 = dn * a3 + dn2 * fmaxf(fmaf(bfhi(yb.y), sc0.w, sh0.w), 0.f);
  float r4 = dn * a4 + dn2 * fmaxf(fmaf(bflo(yb.z), sc1.x, sh1.x), 0.f);
  float r5 = dn * a5 + dn2 * fmaxf(fmaf(bfhi(yb.z), sc1.y, sh1.y), 0.f);
  float r6 = dn * a6 + dn2 * fmaxf(fmaf(bflo(yb.w), sc1.z, sh1.z), 0.f);
  float r7 = dn * a7 + dn2 * fmaxf(fmaf(bfhi(yb.w), sc1.w, sh1.w), 0.f);
  uint4 o;
  o.x = (unsigned)f2bf(r0) | ((unsigned)f2bf(r1) << 16);
  o.y = (unsigned)f2bf(r2) | ((unsigned)f2bf(r3) << 16);
  o.z = (unsigned)f2bf(r4) | ((unsigned)f2bf(r5) << 16);
  o.w = (unsigned)f2bf(r6) | ((unsigned)f2bf(r7) << 16);
  *(uint4*)&Ahi[(size_t)n * 256 + c] = o;
}

// ---------------- MFMA GEMM (r20/r26-measured best: ~55us @29% occ) -------
__global__ __launch_bounds__(256) void k_gemm_mfma(
    const unsigned short* __restrict__ A,
    const unsigned short* __restrict__ Wblk,
    const float* __restrict__ bias, unsigned short* __restrict__ Ybf,
    float* __restrict__ statsP, int M) {
  __shared__ unsigned short Wlds[16384];  // 32KB W slab / epilogue stage
  __shared__ float bstats[512];
  const int tid = threadIdx.x;
  const int lane = tid & 63;
  const int w = tid >> 6;
  const int l15 = lane & 15, lg = lane >> 4;
  const int r0 = blockIdx.x * 64 + w * 16;

  bstats[tid] = 0.f;
  bstats[tid + 256] = 0.f;

  const unsigned short* Ap = A + (size_t)(r0 + l15) * 256 + lg * 8;

  f32x4 acc[16] = {};
#pragma unroll
  for (int t = 0; t < 4; ++t) {
#pragma unroll
    for (int it = 0; it < 8; ++it)
      GLOAD_LDS16(Wblk + t * 16384 + it * 2048 + tid * 8,
                  &Wlds[it * 2048 + tid * 8]);
    bf16x8 a0 = *(const bf16x8*)(Ap + t * 64);
    bf16x8 a1 = *(const bf16x8*)(Ap + t * 64 + 32);
    asm volatile("s_waitcnt vmcnt(0)" ::: "memory");
    __builtin_amdgcn_s_barrier();
#pragma unroll
    for (int kk2 = 0; kk2 < 2; ++kk2) {
      bf16x8 a = kk2 ? a1 : a0;
#pragma unroll
      for (int n = 0; n < 16; ++n) {
        int c = n * 16 + l15;
        bf16x8 b = *(const bf16x8*)&Wlds[c * 64 +
                     ((kk2 * 32 + lg * 8) ^ ((l15 & 7) << 3))];
        acc[n] = __builtin_amdgcn_mfma_f32_16x16x32_bf16(a, b, acc[n], 0, 0, 0);
      }
    }
    asm volatile("s_waitcnt lgkmcnt(0)" ::: "memory");
    __builtin_amdgcn_s_barrier();
  }

  unsigned short* stage = Wlds;  // 64 rows x 256 cols bf16 = 32KB
#pragma unroll
  for (int n = 0; n < 16; ++n) {
    int col = n * 16 + l15;
    float bv = bias[col];
    float s = 0.f, s2 = 0.f;
    f32x4 v = acc[n];
#pragma unroll
    for (int j = 0; j < 4; ++j) {
      float val = v[j] + bv;
      int rl = w * 16 + lg * 4 + j;
      stage[rl * 256 + col] = f2bf(val);
      if (blockIdx.x * 64 + rl < M) { s += val; s2 += val * val; }
    }
    s += __shfl_xor(s, 16);  s += __shfl_xor(s, 32);
    s2 += __shfl_xor(s2, 16); s2 += __shfl_xor(s2, 32);
    if (lg == 0) {
      atomicAdd(&bstats[col], s);
      atomicAdd(&bstats[256 + col], s2);
    }
  }
  __syncthreads();
#pragma unroll
  for (int it = 0; it < 8; ++it) {
    int idx = it * 256 + tid;
    int rl = idx >> 5;
    int c16 = idx & 31;
    int grow = blockIdx.x * 64 + rl;
    if (grow < M)
      *(int4*)((char*)Ybf + (size_t)grow * 512 + c16 * 16) =
          *(const int4*)((const char*)stage + rl * 512 + c16 * 16);
  }
  float* sp = statsP + (blockIdx.x & 7) * 512;
  atomicAdd(&sp[tid], bstats[tid]);
  atomicAdd(&sp[256 + tid], bstats[256 + tid]);
}

// ---------------- BN scale/shift (sums npart partial slices) ----------------
__global__ void k_scaleshift(const float* __restrict__ base, int npart,
                             const float* __restrict__ g,
                             const float* __restrict__ be, float* __restrict__ ss, int N) {
  int c = threadIdx.x;
  float s = 0.f, s2 = 0.f;
  for (int p = 0; p < npart; ++p) {
    s += base[p * 512 + c];
    s2 += base[p * 512 + 256 + c];
  }
  float inv = 1.0f / (float)N;
  float mean = s * inv;
  float var = s2 * inv - mean * mean;
  var = fmaxf(var, 0.f);
  float sc = g[c] * rsqrtf(var + 1e-5f);
  ss[c] = sc;
  ss[256 + c] = be[c] - mean * sc;
}

// ---------------- pooling with fused BN+ReLU, vectorized (r29-measured) -----
__global__ __launch_bounds__(256) void k_pool(const unsigned short* __restrict__ Ybf,
    const float* __restrict__ ss, const int* __restrict__ gstart,
    float* __restrict__ pooled) {
  __shared__ float redS[8][256];
  __shared__ float redM[8][256];
  int g = blockIdx.x;
  int tid = threadIdx.x;
  int grp = tid >> 5;      // 0..7 row-group
  int l32 = tid & 31;
  int c = l32 * 8;
  float4 sc0 = *(const float4*)&ss[c];
  float4 sc1 = *(const float4*)&ss[c + 4];
  float4 sh0 = *(const float4*)&ss[256 + c];
  float4 sh1 = *(const float4*)&ss[256 + c + 4];
  int n0 = gstart[g], n1 = gstart[g + 1];
  float s0 = 0.f, s1 = 0.f, s2 = 0.f, s3 = 0.f, s4 = 0.f, s5 = 0.f, s6 = 0.f, s7 = 0.f;
  float m0 = 0.f, m1 = 0.f, m2 = 0.f, m3 = 0.f, m4 = 0.f, m5 = 0.f, m6 = 0.f, m7 = 0.f;
  for (int n = n0 + grp; n < n1; n += 8) {
    uint4 y = *(const uint4*)&Ybf[(size_t)n * 256 + c];
    float v0 = fmaxf(fmaf(bflo(y.x), sc0.x, sh0.x), 0.f);
    float v1 = fmaxf(fmaf(bfhi(y.x), sc0.y, sh0.y), 0.f);
    float v2 = fmaxf(fmaf(bflo(y.y), sc0.z, sh0.z), 0.f);
    float v3 = fmaxf(fmaf(bfhi(y.y), sc0.w, sh0.w), 0.f);
    float v4 = fmaxf(fmaf(bflo(y.z), sc1.x, sh1.x), 0.f);
    float v5 = fmaxf(fmaf(bfhi(y.z), sc1.y, sh1.y), 0.f);
    float v6 = fmaxf(fmaf(bflo(y.w), sc1.z, sh1.z), 0.f);
    float v7 = fmaxf(fmaf(bfhi(y.w), sc1.w, sh1.w), 0.f);
    s0 += v0; m0 = fmaxf(m0, v0);
    s1 += v1; m1 = fmaxf(m1, v1);
    s2 += v2; m2 = fmaxf(m2, v2);
    s3 += v3; m3 = fmaxf(m3, v3);
    s4 += v4; m4 = fmaxf(m4, v4);
    s5 += v5; m5 = fmaxf(m5, v5);
    s6 += v6; m6 = fmaxf(m6, v6);
    s7 += v7; m7 = fmaxf(m7, v7);
  }
  redS[grp][c + 0] = s0; redM[grp][c + 0] = m0;
  redS[grp][c + 1] = s1; redM[grp][c + 1] = m1;
  redS[grp][c + 2] = s2; redM[grp][c + 2] = m2;
  redS[grp][c + 3] = s3; redM[grp][c + 3] = m3;
  redS[grp][c + 4] = s4; redM[grp][c + 4] = m4;
  redS[grp][c + 5] = s5; redM[grp][c + 5] = m5;
  redS[grp][c + 6] = s6; redM[grp][c + 6] = m6;
  redS[grp][c + 7] = s7; redM[grp][c + 7] = m7;
  __syncthreads();
  float s = 0.f, m = 0.f;
#pragma unroll
  for (int k = 0; k < 8; ++k) {
    s += redS[k][tid];
    m = fmaxf(m, redM[k][tid]);
  }
  float cnt = (float)(n1 - n0);
  pooled[g * 512 + tid] = s / fmaxf(cnt, 1.0f);
  pooled[g * 512 + 256 + tid] = m;
}

// ---------------- MLP + fused tail (mlp2 + heads) ----------------
__global__ __launch_bounds__(256) void k_mlp1(const float* __restrict__ P,
    const float* __restrict__ W, const float* __restrict__ b, float* __restrict__ O) {
  __shared__ float Ps[4 * 512];
  int tid = threadIdx.x;
  int g0 = blockIdx.x * 4;
  for (int j = 0; j < 8; ++j) Ps[j * 256 + tid] = P[g0 * 512 + j * 256 + tid];
  __syncthreads();
  float acc[4];
  float bb = b[tid];
#pragma unroll
  for (int gi = 0; gi < 4; ++gi) acc[gi] = bb;
  for (int k = 0; k < 512; ++k) {
    float w = W[k * 256 + tid];
#pragma unroll
    for (int gi = 0; gi < 4; ++gi) acc[gi] += Ps[gi * 512 + k] * w;
  }
#pragma unroll
  for (int gi = 0; gi < 4; ++gi)
    O[(g0 + gi) * 256 + tid] = fmaxf(acc[gi], 0.f);
}

// fused mlp2 + heads: 2 graphs per block, 128 threads.
// mlp2 math identical to prior k_mlp2 (k 0..255 sequential per channel);
// heads math identical to prior k_heads (k 0..127, o 0..31 sequential).
__global__ __launch_bounds__(128) void k_tail(const float* __restrict__ S,
    const float* __restrict__ W, const float* __restrict__ b,
    const float* __restrict__ hW1, const float* __restrict__ hb1,
    const float* __restrict__ hW2, const float* __restrict__ hb2,
    float* __restrict__ out) {
  __shared__ float Ss[2 * 256];
  __shared__ float s2s[2][128];
  __shared__ float t1s[2][96];
  int tid = threadIdx.x;
  int g0 = blockIdx.x * 2;
  for (int j = 0; j < 4; ++j) Ss[j * 128 + tid] = S[g0 * 256 + j * 128 + tid];
  __syncthreads();
  float bb = b[tid];
  float acc0 = bb, acc1 = bb;
  for (int k = 0; k < 256; ++k) {
    float w = W[k * 128 + tid];
    acc0 += Ss[k] * w;
    acc1 += Ss[256 + k] * w;
  }
  s2s[0][tid] = fmaxf(acc0, 0.f);
  s2s[1][tid] = fmaxf(acc1, 0.f);
  __syncthreads();
  if (tid < 96) {
    int t = tid >> 5, o = tid & 31;
    float hb = hb1[t * 32 + o];
    float a0 = hb, a1 = hb;
    for (int k = 0; k < 128; ++k) {
      float w = hW1[t * 4096 + k * 32 + o];
      a0 += s2s[0][k] * w;
      a1 += s2s[1][k] * w;
    }
    t1s[0][tid] = fmaxf(a0, 0.f);
    t1s[1][tid] = fmaxf(a1, 0.f);
  }
  __syncthreads();
  if (tid < 6) {
    int p = tid / 3, t = tid - p * 3;
    float acc = hb2[t];
    for (int o = 0; o < 32; ++o) acc += t1s[p][t * 32 + o] * hW2[t * 32 + o];
    out[t * NGRAPH + g0 + p] = acc;
  }
}

// ---------------- host launcher ----------------
extern "C" void kernel_launch(void* const* d_in, const int* in_sizes, int n_in,
                              void* d_out, int out_size, void* d_ws, size_t ws_size,
                              hipStream_t stream) {
  const float* x   = (const float*)d_in[0];
  const int* ei    = (const int*)d_in[1];
  const int* batch = (const int*)d_in[2];
  const float* W1 = (const float*)d_in[3];  const float* b1 = (const float*)d_in[4];
  const float* W2 = (const float*)d_in[5];  const float* b2 = (const float*)d_in[6];
  const float* W3 = (const float*)d_in[7];  const float* b3 = (const float*)d_in[8];
  const float* W4 = (const float*)d_in[9];  const float* b4 = (const float*)d_in[10];
  const float* g1 = (const float*)d_in[11]; const float* be1 = (const float*)d_in[12];
  const float* g2 = (const float*)d_in[13]; const float* be2 = (const float*)d_in[14];
  const float* g3 = (const float*)d_in[15]; const float* be3 = (const float*)d_in[16];
  const float* g4 = (const float*)d_in[17]; const float* be4 = (const float*)d_in[18];
  const float* sW1 = (const float*)d_in[19]; const float* sb1 = (const float*)d_in[20];
  const float* sW2 = (const float*)d_in[21]; const float* sb2 = (const float*)d_in[22];
  const float* hW1 = (const float*)d_in[23]; const float* hb1 = (const float*)d_in[24];
  const float* hW2 = (const float*)d_in[25]; const float* hb2 = (const float*)d_in[26];

  const int N = in_sizes[0] / 8;
  const int E = in_sizes[1] / 2;
  const int Npad = (N + 127) & ~127;
  const int* srcp = ei;
  const int* dstp = ei + E;

  char* base = (char*)d_ws;
  size_t off = 0;
  auto alloc = [&](size_t bytes) -> void* {
    void* p = base + off;
    off += (bytes + 255) & ~(size_t)255;
    return p;
  };
  unsigned short* Ybf = (unsigned short*)alloc((size_t)Npad * 256 * 2);
  unsigned short* Ahi = (unsigned short*)alloc((size_t)Npad * 256 * 2);
  float* dis  = (float*)alloc((size_t)N * 4);
  int* cnt    = (int*)alloc((size_t)N * 4);
  int* rs     = (int*)alloc((size_t)(N + 1) * 4);
  int* cursor = (int*)alloc((size_t)N * 4);
  int* es     = (int*)alloc((size_t)E * 4);
  int* bsum   = (int*)alloc(1024 * 4);
  int* bsumx  = (int*)alloc(1032 * 4);
  float* xa8  = (float*)alloc((size_t)N * 8 * 4);
  float* statsAll = (float*)alloc(2048 * 4);
  float* statsP   = (float*)alloc(12288 * 4);   // 3 layers x 8 slices x 512
  float* ssAll    = (float*)alloc(2048 * 4);
  unsigned short* Wblk = (unsigned short*)alloc(3 * 256 * 256 * 2);
  int* cntg    = (int*)alloc(2048 * 4);
  int* gstart  = (int*)alloc(2049 * 4);
  float* pooled = (float*)alloc((size_t)2048 * 512 * 4);
  float* s1b    = (float*)alloc((size_t)2048 * 256 * 4);
  (void)ws_size; (void)n_in; (void)out_size;

  int nb = (N + TPB - 1) / TPB;
  int eb = (E + TPB - 1) / TPB;
  int nblocks1 = (N + 1023) / 1024;

  k_init<<<nb, TPB, 0, stream>>>(dis, cnt, cntg, statsAll, statsP, N);
  k_hist<<<eb, TPB, 0, stream>>>(dstp, dis, cnt, batch, cntg, E, N);
  k_scan1<<<nblocks1, 256, 0, stream>>>(cnt, rs, bsum, N);
  k_scan_small2<<<2, 256, 0, stream>>>(bsum, bsumx, nblocks1, cntg, gstart, NGRAPH);
  k_scan3<<<nb, TPB, 0, stream>>>(rs, bsumx, cursor, dis, N, E);
  k_scatter<<<eb, TPB, 0, stream>>>(srcp, dstp, cursor, es, E);

  // weight prep (layers 2..4) in one launch: K=64-blocked + swizzle-baked bf16
  k_wprep2<<<768, 256, 0, stream>>>(W2, W3, W4, Wblk);

  // ---- layer 1: aggregate on D=8, project (fp32), fused stats ----
  k_agg8<<<(N * 8 + TPB - 1) / TPB, TPB, 0, stream>>>(x, dis, rs, es, xa8, N);
  k_gemm8<<<(N + 63) / 64, 256, 0, stream>>>(xa8, W1, b1, Ybf, statsAll, N);
  k_scaleshift<<<1, 256, 0, stream>>>(statsAll, 1, g1, be1, ssAll, N);

  // ---- layers 2..4 ----
  const float* bs_[3] = {b2, b3, b4};
  const float* gs[3]  = {g2, g3, g4};
  const float* bes[3] = {be2, be3, be4};
  for (int L = 0; L < 3; ++L) {
    k_agg_bn<<<(N + 7) / 8, 256, 0, stream>>>(Ybf, ssAll + L * 512, dis, rs, es,
                                              Ahi, N);
    k_gemm_mfma<<<(N + 63) / 64, 256, 0, stream>>>(Ahi, Wblk + L * 65536,
                                                   bs_[L], Ybf, statsP + L * 4096, N);
    k_scaleshift<<<1, 256, 0, stream>>>(statsP + L * 4096, 8, gs[L], bes[L],
                                        ssAll + (L + 1) * 512, N);
  }

  // ---- pooling (fused BN+ReLU of layer 4) + MLP + fused tail ----
  k_pool<<<NGRAPH, 256, 0, stream>>>(Ybf, ssAll + 3 * 512, gstart, pooled);
  k_mlp1<<<NGRAPH / 4, 256, 0, stream>>>(pooled, sW1, sb1, s1b);
  k_tail<<<NGRAPH / 2, 128, 0, stream>>>(s1b, sW2, sb2, hW1, hb1, hW2, hb2,
                                         (float*)d_out);
}

// Round 35
// 467.263 us; speedup vs baseline: 2.2985x; 1.0077x over previous
//
#include <hip/hip_runtime.h>
#include <math.h>

#define TPB 256
#define NGRAPH 2048

typedef __attribute__((ext_vector_type(8))) short bf16x8;
typedef __attribute__((ext_vector_type(4))) float f32x4;

__device__ __forceinline__ unsigned short f2bf(float f) {
  unsigned u = __float_as_uint(f);
  unsigned r = (u + 0x7FFF + ((u >> 16) & 1)) >> 16;
  return (unsigned short)r;
}
__device__ __forceinline__ float bf2f(unsigned short h) {
  return __uint_as_float(((unsigned)h) << 16);
}
__device__ __forceinline__ float bflo(unsigned u) {
  return __uint_as_float(u << 16);
}
__device__ __forceinline__ float bfhi(unsigned u) {
  return __uint_as_float(u & 0xFFFF0000u);
}

#define GLOAD_LDS16(G, L) \
  __builtin_amdgcn_global_load_lds((const __attribute__((address_space(1))) unsigned int*)(G), \
                                   (__attribute__((address_space(3))) unsigned int*)(L), 16, 0, 0)

// ---------------- init / degree / histograms ----------------
__global__ void k_init(float* __restrict__ deg, int* __restrict__ cnt,
                       int* __restrict__ cntg, float* __restrict__ statsAll,
                       float* __restrict__ statsP, int N) {
  int i = blockIdx.x * TPB + threadIdx.x;
  if (i < N) { deg[i] = 1.0f; cnt[i] = 0; }
  if (i < NGRAPH) cntg[i] = 0;
  if (i < 2048) statsAll[i] = 0.f;
  if (i < 12288) statsP[i] = 0.f;
}

// fused: edge-degree histogram (over E) + graph-size histogram (over N)
__global__ void k_hist(const int* __restrict__ dst, float* __restrict__ deg,
                       int* __restrict__ cnt, const int* __restrict__ batch,
                       int* __restrict__ cntg, int E, int N) {
  int i = blockIdx.x * TPB + threadIdx.x;
  if (i < E) {
    int d = dst[i];
    atomicAdd(&deg[d], 1.0f);
    atomicAdd(&cnt[d], 1);
  }
  if (i < N) atomicAdd(&cntg[batch[i]], 1);
}

// ---------------- scans ----------------
__global__ void k_scan1(const int* __restrict__ in, int* __restrict__ out,
                        int* __restrict__ bsum, int n) {
  __shared__ int ts[256];
  int tid = threadIdx.x;
  int base = blockIdx.x * 1024 + tid * 4;
  int v0 = (base + 0 < n) ? in[base + 0] : 0;
  int v1 = (base + 1 < n) ? in[base + 1] : 0;
  int v2 = (base + 2 < n) ? in[base + 2] : 0;
  int v3 = (base + 3 < n) ? in[base + 3] : 0;
  int s = v0 + v1 + v2 + v3;
  int run = s;
  ts[tid] = run; __syncthreads();
  for (int off = 1; off < 256; off <<= 1) {
    int add = (tid >= off) ? ts[tid - off] : 0;
    __syncthreads();
    run += add; ts[tid] = run; __syncthreads();
  }
  int acc = run - s;
  if (base + 0 < n) out[base + 0] = acc; acc += v0;
  if (base + 1 < n) out[base + 1] = acc; acc += v1;
  if (base + 2 < n) out[base + 2] = acc; acc += v2;
  if (base + 3 < n) out[base + 3] = acc;
  if (tid == 255) bsum[blockIdx.x] = run;
}

// dual single-block exclusive scan: block 0 scans (inA,nA)->dstA, block 1
// scans (inB,nB)->dstB. Both inputs are ready when this launches.
__global__ void k_scan_small2(const int* __restrict__ inA, int* __restrict__ dstA, int nA,
                              const int* __restrict__ inB, int* __restrict__ dstB, int nB) {
  __shared__ int ts[256];
  const int* in = (blockIdx.x == 0) ? inA : inB;
  int* dst      = (blockIdx.x == 0) ? dstA : dstB;
  int n         = (blockIdx.x == 0) ? nA : nB;
  int tid = threadIdx.x;
  int chunk = (n + 255) >> 8;
  int start = tid * chunk;
  int s = 0;
  for (int j = 0; j < chunk; ++j) { int idx = start + j; if (idx < n) s += in[idx]; }
  int run = s;
  ts[tid] = run; __syncthreads();
  for (int off = 1; off < 256; off <<= 1) {
    int add = (tid >= off) ? ts[tid - off] : 0;
    __syncthreads();
    run += add; ts[tid] = run; __syncthreads();
  }
  int acc = run - s;
  for (int j = 0; j < chunk; ++j) {
    int idx = start + j;
    if (idx < n) { dst[idx] = acc; acc += in[idx]; }
  }
  if (tid == 255) dst[n] = run;
}

// scan finalize + fused rsqrt(deg) -> dis (deg final since k_hist completed)
__global__ void k_scan3(int* __restrict__ rs, const int* __restrict__ bsumx,
                        int* __restrict__ cursor, float* __restrict__ dis,
                        int n, int total) {
  int i = blockIdx.x * TPB + threadIdx.x;
  if (i < n) {
    int v = rs[i] + bsumx[i >> 10];
    rs[i] = v; cursor[i] = v;
    dis[i] = rsqrtf(dis[i]);
  }
  if (i == 0) rs[n] = total;
}

__global__ void k_scatter(const int* __restrict__ src, const int* __restrict__ dst,
                          int* __restrict__ cursor, int* __restrict__ es, int E) {
  int e = blockIdx.x * TPB + threadIdx.x;
  if (e < E) {
    int d = dst[e];
    int p = atomicAdd(&cursor[d], 1);
    es[p] = src[e];
  }
}

// ------- weight prep: all 3 layers in one launch (grid 768) ----------------
// K=64-blocked transposed layout, swizzle pre-baked.
__global__ __launch_bounds__(256) void k_wprep2(const float* __restrict__ W2,
    const float* __restrict__ W3, const float* __restrict__ W4,
    unsigned short* __restrict__ Wblk) {
  int L = blockIdx.x >> 8;          // 0..2
  int c = blockIdx.x & 255;
  int k = threadIdx.x;
  const float* W = (L == 0) ? W2 : (L == 1) ? W3 : W4;
  float w = W[k * 256 + c];
  int t = k >> 6, kl = k & 63;
  Wblk[L * 65536 + t * 16384 + c * 64 + (kl ^ ((c & 7) << 3))] = f2bf(w);
}

// ---- layer 1 fused: aggregate on D=8 inline + project + BN stats ----------
// rows[idx] (idx = node_local*8 + c) computed in-kernel, replacing k_agg8:
// identical math order (edges e0..e1 sequential, then dn*acc + dn^2*x).
__global__ __launch_bounds__(256) void k_gemm8(const float* __restrict__ x,
    const float* __restrict__ dis, const int* __restrict__ rs,
    const int* __restrict__ es,
    const float* __restrict__ W, const float* __restrict__ b,
    unsigned short* __restrict__ Ybf, float* __restrict__ stats, int N) {
  __shared__ float Ws[8 * 256];
  __shared__ float bs[256];
  __shared__ float rows[64 * 8];
  int tid = threadIdx.x;
  int row0 = blockIdx.x * 64;
  for (int j = 0; j < 8; ++j) Ws[tid + j * 256] = W[tid + j * 256];
  bs[tid] = b[tid];
#pragma unroll
  for (int half = 0; half < 2; ++half) {
    int idx = tid + half * 256;
    int n = row0 + (idx >> 3);
    int c = idx & 7;
    float val = 0.f;
    if (n < N) {
      int e0 = rs[n], e1 = rs[n + 1];
      float acc = 0.f;
      for (int e = e0; e < e1; ++e) {
        int s = es[e];
        acc += dis[s] * x[s * 8 + c];
      }
      float dn = dis[n];
      val = dn * acc + dn * dn * x[n * 8 + c];
    }
    rows[idx] = val;
  }
  __syncthreads();
  float bb = bs[tid];
  float s = 0.f, s2 = 0.f;
  for (int r = 0; r < 64; r += 2) {
    int rowA = row0 + r, rowB = rowA + 1;
    float a0 = bb, a1 = bb;
#pragma unroll
    for (int k = 0; k < 8; ++k) {
      a0 = fmaf(rows[r * 8 + k], Ws[k * 256 + tid], a0);
      a1 = fmaf(rows[r * 8 + 8 + k], Ws[k * 256 + tid], a1);
    }
    if (rowA < N) {
      Ybf[(size_t)rowA * 256 + tid] = f2bf(a0);
      s += a0; s2 += a0 * a0;
    }
    if (rowB < N) {
      Ybf[(size_t)rowB * 256 + tid] = f2bf(a1);
      s += a1; s2 += a1 * a1;
    }
  }
  atomicAdd(&stats[tid], s);
  atomicAdd(&stats[256 + tid], s2);
}

// ------- fused BN+ReLU aggregation, half-wave per node (r22-measured) ------
__global__ __launch_bounds__(256) void k_agg_bn(const unsigned short* __restrict__ Ybf,
    const float* __restrict__ ss, const float* __restrict__ dis,
    const int* __restrict__ rs, const int* __restrict__ es,
    unsigned short* __restrict__ Ahi, int N) {
  int l32 = threadIdx.x & 31;
  int n = blockIdx.x * 8 + (threadIdx.x >> 5);
  if (n >= N) return;
  int c = l32 * 8;
  float4 sc0 = *(const float4*)&ss[c];
  float4 sc1 = *(const float4*)&ss[c + 4];
  float4 sh0 = *(const float4*)&ss[256 + c];
  float4 sh1 = *(const float4*)&ss[256 + c + 4];
  int e0 = rs[n], e1 = rs[n + 1];
  float a0 = 0.f, a1 = 0.f, a2 = 0.f, a3 = 0.f;
  float a4 = 0.f, a5 = 0.f, a6 = 0.f, a7 = 0.f;
#define BNR8(Q, d)                                                           \
  {                                                                          \
    a0 += (d) * fmaxf(fmaf(bflo(Q.x), sc0.x, sh0.x), 0.f);                   \
    a1 += (d) * fmaxf(fmaf(bfhi(Q.x), sc0.y, sh0.y), 0.f);                   \
    a2 += (d) * fmaxf(fmaf(bflo(Q.y), sc0.z, sh0.z), 0.f);                   \
    a3 += (d) * fmaxf(fmaf(bfhi(Q.y), sc0.w, sh0.w), 0.f);                   \
    a4 += (d) * fmaxf(fmaf(bflo(Q.z), sc1.x, sh1.x), 0.f);                   \
    a5 += (d) * fmaxf(fmaf(bfhi(Q.z), sc1.y, sh1.y), 0.f);                   \
    a6 += (d) * fmaxf(fmaf(bflo(Q.w), sc1.z, sh1.z), 0.f);                   \
    a7 += (d) * fmaxf(fmaf(bfhi(Q.w), sc1.w, sh1.w), 0.f);                   \
  }
  int e = e0;
  for (; e + 2 <= e1; e += 2) {
    int s0 = es[e], s1 = es[e + 1];
    float d0 = dis[s0], d1 = dis[s1];
    uint4 y0 = *(const uint4*)&Ybf[(size_t)s0 * 256 + c];
    uint4 y1 = *(const uint4*)&Ybf[(size_t)s1 * 256 + c];
    BNR8(y0, d0);
    BNR8(y1, d1);
  }
  if (e < e1) {
    int s0 = es[e];
    float d0 = dis[s0];
    uint4 y0 = *(const uint4*)&Ybf[(size_t)s0 * 256 + c];
    BNR8(y0, d0);
  }
#undef BNR8
  float dn = dis[n];
  float dn2 = dn * dn;
  uint4 yb = *(const uint4*)&Ybf[(size_t)n * 256 + c];
  float r0 = dn * a0 + dn2 * fmaxf(fmaf(bflo(yb.x), sc0.x, sh0.x), 0.f);
  float r1 = dn * a1 + dn2 * fmaxf(fmaf(bfhi(yb.x), sc0.y, sh0.y), 0.f);
  float r2 = dn * a2 + dn2 * fmaxf(fmaf(bflo(yb.y), sc0.z, sh0.z), 0.f);
  float r3 = dn * a3 + dn2 * fmaxf(fmaf(bfhi(yb.y), sc0.w, sh0.w), 0.f);
  float r4 = dn * a4 + dn2 * fmaxf(fmaf(bflo(yb.z), sc1.x, sh1.x), 0.f);
  float r5 = dn * a5 + dn2 * fmaxf(fmaf(bfhi(yb.z), sc1.y, sh1.y), 0.f);
  float r6 = dn * a6 + dn2 * fmaxf(fmaf(bflo(yb.w), sc1.z, sh1.z), 0.f);
  float r7 = dn * a7 + dn2 * fmaxf(fmaf(bfhi(yb.w), sc1.w, sh1.w), 0.f);
  uint4 o;
  o.x = (unsigned)f2bf(r0) | ((unsigned)f2bf(r1) << 16);
  o.y = (unsigned)f2bf(r2) | ((unsigned)f2bf(r3) << 16);
  o.z = (unsigned)f2bf(r4) | ((unsigned)f2bf(r5) << 16);
  o.w = (unsigned)f2bf(r6) | ((unsigned)f2bf(r7) << 16);
  *(uint4*)&Ahi[(size_t)n * 256 + c] = o;
}

// ---------------- MFMA GEMM (r20/r26-measured best: ~55us @29% occ) -------
__global__ __launch_bounds__(256) void k_gemm_mfma(
    const unsigned short* __restrict__ A,
    const unsigned short* __restrict__ Wblk,
    const float* __restrict__ bias, unsigned short* __restrict__ Ybf,
    float* __restrict__ statsP, int M) {
  __shared__ unsigned short Wlds[16384];  // 32KB W slab / epilogue stage
  __shared__ float bstats[512];
  const int tid = threadIdx.x;
  const int lane = tid & 63;
  const int w = tid >> 6;
  const int l15 = lane & 15, lg = lane >> 4;
  const int r0 = blockIdx.x * 64 + w * 16;

  bstats[tid] = 0.f;
  bstats[tid + 256] = 0.f;

  const unsigned short* Ap = A + (size_t)(r0 + l15) * 256 + lg * 8;

  f32x4 acc[16] = {};
#pragma unroll
  for (int t = 0; t < 4; ++t) {
#pragma unroll
    for (int it = 0; it < 8; ++it)
      GLOAD_LDS16(Wblk + t * 16384 + it * 2048 + tid * 8,
                  &Wlds[it * 2048 + tid * 8]);
    bf16x8 a0 = *(const bf16x8*)(Ap + t * 64);
    bf16x8 a1 = *(const bf16x8*)(Ap + t * 64 + 32);
    asm volatile("s_waitcnt vmcnt(0)" ::: "memory");
    __builtin_amdgcn_s_barrier();
#pragma unroll
    for (int kk2 = 0; kk2 < 2; ++kk2) {
      bf16x8 a = kk2 ? a1 : a0;
#pragma unroll
      for (int n = 0; n < 16; ++n) {
        int c = n * 16 + l15;
        bf16x8 b = *(const bf16x8*)&Wlds[c * 64 +
                     ((kk2 * 32 + lg * 8) ^ ((l15 & 7) << 3))];
        acc[n] = __builtin_amdgcn_mfma_f32_16x16x32_bf16(a, b, acc[n], 0, 0, 0);
      }
    }
    asm volatile("s_waitcnt lgkmcnt(0)" ::: "memory");
    __builtin_amdgcn_s_barrier();
  }

  unsigned short* stage = Wlds;  // 64 rows x 256 cols bf16 = 32KB
#pragma unroll
  for (int n = 0; n < 16; ++n) {
    int col = n * 16 + l15;
    float bv = bias[col];
    float s = 0.f, s2 = 0.f;
    f32x4 v = acc[n];
#pragma unroll
    for (int j = 0; j < 4; ++j) {
      float val = v[j] + bv;
      int rl = w * 16 + lg * 4 + j;
      stage[rl * 256 + col] = f2bf(val);
      if (blockIdx.x * 64 + rl < M) { s += val; s2 += val * val; }
    }
    s += __shfl_xor(s, 16);  s += __shfl_xor(s, 32);
    s2 += __shfl_xor(s2, 16); s2 += __shfl_xor(s2, 32);
    if (lg == 0) {
      atomicAdd(&bstats[col], s);
      atomicAdd(&bstats[256 + col], s2);
    }
  }
  __syncthreads();
#pragma unroll
  for (int it = 0; it < 8; ++it) {
    int idx = it * 256 + tid;
    int rl = idx >> 5;
    int c16 = idx & 31;
    int grow = blockIdx.x * 64 + rl;
    if (grow < M)
      *(int4*)((char*)Ybf + (size_t)grow * 512 + c16 * 16) =
          *(const int4*)((const char*)stage + rl * 512 + c16 * 16);
  }
  float* sp = statsP + (blockIdx.x & 7) * 512;
  atomicAdd(&sp[tid], bstats[tid]);
  atomicAdd(&sp[256 + tid], bstats[256 + tid]);
}

// ---------------- BN scale/shift (sums npart partial slices) ----------------
__global__ void k_scaleshift(const float* __restrict__ base, int npart,
                             const float* __restrict__ g,
                             const float* __restrict__ be, float* __restrict__ ss, int N) {
  int c = threadIdx.x;
  float s = 0.f, s2 = 0.f;
  for (int p = 0; p < npart; ++p) {
    s += base[p * 512 + c];
    s2 += base[p * 512 + 256 + c];
  }
  float inv = 1.0f / (float)N;
  float mean = s * inv;
  float var = s2 * inv - mean * mean;
  var = fmaxf(var, 0.f);
  float sc = g[c] * rsqrtf(var + 1e-5f);
  ss[c] = sc;
  ss[256 + c] = be[c] - mean * sc;
}

// ---------------- pooling with fused BN+ReLU, vectorized (r29-measured) -----
__global__ __launch_bounds__(256) void k_pool(const unsigned short* __restrict__ Ybf,
    const float* __restrict__ ss, const int* __restrict__ gstart,
    float* __restrict__ pooled) {
  __shared__ float redS[8][256];
  __shared__ float redM[8][256];
  int g = blockIdx.x;
  int tid = threadIdx.x;
  int grp = tid >> 5;      // 0..7 row-group
  int l32 = tid & 31;
  int c = l32 * 8;
  float4 sc0 = *(const float4*)&ss[c];
  float4 sc1 = *(const float4*)&ss[c + 4];
  float4 sh0 = *(const float4*)&ss[256 + c];
  float4 sh1 = *(const float4*)&ss[256 + c + 4];
  int n0 = gstart[g], n1 = gstart[g + 1];
  float s0 = 0.f, s1 = 0.f, s2 = 0.f, s3 = 0.f, s4 = 0.f, s5 = 0.f, s6 = 0.f, s7 = 0.f;
  float m0 = 0.f, m1 = 0.f, m2 = 0.f, m3 = 0.f, m4 = 0.f, m5 = 0.f, m6 = 0.f, m7 = 0.f;
  for (int n = n0 + grp; n < n1; n += 8) {
    uint4 y = *(const uint4*)&Ybf[(size_t)n * 256 + c];
    float v0 = fmaxf(fmaf(bflo(y.x), sc0.x, sh0.x), 0.f);
    float v1 = fmaxf(fmaf(bfhi(y.x), sc0.y, sh0.y), 0.f);
    float v2 = fmaxf(fmaf(bflo(y.y), sc0.z, sh0.z), 0.f);
    float v3 = fmaxf(fmaf(bfhi(y.y), sc0.w, sh0.w), 0.f);
    float v4 = fmaxf(fmaf(bflo(y.z), sc1.x, sh1.x), 0.f);
    float v5 = fmaxf(fmaf(bfhi(y.z), sc1.y, sh1.y), 0.f);
    float v6 = fmaxf(fmaf(bflo(y.w), sc1.z, sh1.z), 0.f);
    float v7 = fmaxf(fmaf(bfhi(y.w), sc1.w, sh1.w), 0.f);
    s0 += v0; m0 = fmaxf(m0, v0);
    s1 += v1; m1 = fmaxf(m1, v1);
    s2 += v2; m2 = fmaxf(m2, v2);
    s3 += v3; m3 = fmaxf(m3, v3);
    s4 += v4; m4 = fmaxf(m4, v4);
    s5 += v5; m5 = fmaxf(m5, v5);
    s6 += v6; m6 = fmaxf(m6, v6);
    s7 += v7; m7 = fmaxf(m7, v7);
  }
  redS[grp][c + 0] = s0; redM[grp][c + 0] = m0;
  redS[grp][c + 1] = s1; redM[grp][c + 1] = m1;
  redS[grp][c + 2] = s2; redM[grp][c + 2] = m2;
  redS[grp][c + 3] = s3; redM[grp][c + 3] = m3;
  redS[grp][c + 4] = s4; redM[grp][c + 4] = m4;
  redS[grp][c + 5] = s5; redM[grp][c + 5] = m5;
  redS[grp][c + 6] = s6; redM[grp][c + 6] = m6;
  redS[grp][c + 7] = s7; redM[grp][c + 7] = m7;
  __syncthreads();
  float s = 0.f, m = 0.f;
#pragma unroll
  for (int k = 0; k < 8; ++k) {
    s += redS[k][tid];
    m = fmaxf(m, redM[k][tid]);
  }
  float cnt = (float)(n1 - n0);
  pooled[g * 512 + tid] = s / fmaxf(cnt, 1.0f);
  pooled[g * 512 + 256 + tid] = m;
}

// ---------------- MLP + fused tail (mlp2 + heads) ----------------
__global__ __launch_bounds__(256) void k_mlp1(const float* __restrict__ P,
    const float* __restrict__ W, const float* __restrict__ b, float* __restrict__ O) {
  __shared__ float Ps[4 * 512];
  int tid = threadIdx.x;
  int g0 = blockIdx.x * 4;
  for (int j = 0; j < 8; ++j) Ps[j * 256 + tid] = P[g0 * 512 + j * 256 + tid];
  __syncthreads();
  float acc[4];
  float bb = b[tid];
#pragma unroll
  for (int gi = 0; gi < 4; ++gi) acc[gi] = bb;
  for (int k = 0; k < 512; ++k) {
    float w = W[k * 256 + tid];
#pragma unroll
    for (int gi = 0; gi < 4; ++gi) acc[gi] += Ps[gi * 512 + k] * w;
  }
#pragma unroll
  for (int gi = 0; gi < 4; ++gi)
    O[(g0 + gi) * 256 + tid] = fmaxf(acc[gi], 0.f);
}

// fused mlp2 + heads: 2 graphs per block, 128 threads.
__global__ __launch_bounds__(128) void k_tail(const float* __restrict__ S,
    const float* __restrict__ W, const float* __restrict__ b,
    const float* __restrict__ hW1, const float* __restrict__ hb1,
    const float* __restrict__ hW2, const float* __restrict__ hb2,
    float* __restrict__ out) {
  __shared__ float Ss[2 * 256];
  __shared__ float s2s[2][128];
  __shared__ float t1s[2][96];
  int tid = threadIdx.x;
  int g0 = blockIdx.x * 2;
  for (int j = 0; j < 4; ++j) Ss[j * 128 + tid] = S[g0 * 256 + j * 128 + tid];
  __syncthreads();
  float bb = b[tid];
  float acc0 = bb, acc1 = bb;
  for (int k = 0; k < 256; ++k) {
    float w = W[k * 128 + tid];
    acc0 += Ss[k] * w;
    acc1 += Ss[256 + k] * w;
  }
  s2s[0][tid] = fmaxf(acc0, 0.f);
  s2s[1][tid] = fmaxf(acc1, 0.f);
  __syncthreads();
  if (tid < 96) {
    int t = tid >> 5, o = tid & 31;
    float hb = hb1[t * 32 + o];
    float a0 = hb, a1 = hb;
    for (int k = 0; k < 128; ++k) {
      float w = hW1[t * 4096 + k * 32 + o];
      a0 += s2s[0][k] * w;
      a1 += s2s[1][k] * w;
    }
    t1s[0][tid] = fmaxf(a0, 0.f);
    t1s[1][tid] = fmaxf(a1, 0.f);
  }
  __syncthreads();
  if (tid < 6) {
    int p = tid / 3, t = tid - p * 3;
    float acc = hb2[t];
    for (int o = 0; o < 32; ++o) acc += t1s[p][t * 32 + o] * hW2[t * 32 + o];
    out[t * NGRAPH + g0 + p] = acc;
  }
}

// ---------------- host launcher ----------------
extern "C" void kernel_launch(void* const* d_in, const int* in_sizes, int n_in,
                              void* d_out, int out_size, void* d_ws, size_t ws_size,
                              hipStream_t stream) {
  const float* x   = (const float*)d_in[0];
  const int* ei    = (const int*)d_in[1];
  const int* batch = (const int*)d_in[2];
  const float* W1 = (const float*)d_in[3];  const float* b1 = (const float*)d_in[4];
  const float* W2 = (const float*)d_in[5];  const float* b2 = (const float*)d_in[6];
  const float* W3 = (const float*)d_in[7];  const float* b3 = (const float*)d_in[8];
  const float* W4 = (const float*)d_in[9];  const float* b4 = (const float*)d_in[10];
  const float* g1 = (const float*)d_in[11]; const float* be1 = (const float*)d_in[12];
  const float* g2 = (const float*)d_in[13]; const float* be2 = (const float*)d_in[14];
  const float* g3 = (const float*)d_in[15]; const float* be3 = (const float*)d_in[16];
  const float* g4 = (const float*)d_in[17]; const float* be4 = (const float*)d_in[18];
  const float* sW1 = (const float*)d_in[19]; const float* sb1 = (const float*)d_in[20];
  const float* sW2 = (const float*)d_in[21]; const float* sb2 = (const float*)d_in[22];
  const float* hW1 = (const float*)d_in[23]; const float* hb1 = (const float*)d_in[24];
  const float* hW2 = (const float*)d_in[25]; const float* hb2 = (const float*)d_in[26];

  const int N = in_sizes[0] / 8;
  const int E = in_sizes[1] / 2;
  const int Npad = (N + 127) & ~127;
  const int* srcp = ei;
  const int* dstp = ei + E;

  char* base = (char*)d_ws;
  size_t off = 0;
  auto alloc = [&](size_t bytes) -> void* {
    void* p = base + off;
    off += (bytes + 255) & ~(size_t)255;
    return p;
  };
  unsigned short* Ybf = (unsigned short*)alloc((size_t)Npad * 256 * 2);
  unsigned short* Ahi = (unsigned short*)alloc((size_t)Npad * 256 * 2);
  float* dis  = (float*)alloc((size_t)N * 4);
  int* cnt    = (int*)alloc((size_t)N * 4);
  int* rs     = (int*)alloc((size_t)(N + 1) * 4);
  int* cursor = (int*)alloc((size_t)N * 4);
  int* es     = (int*)alloc((size_t)E * 4);
  int* bsum   = (int*)alloc(1024 * 4);
  int* bsumx  = (int*)alloc(1032 * 4);
  float* statsAll = (float*)alloc(2048 * 4);
  float* statsP   = (float*)alloc(12288 * 4);   // 3 layers x 8 slices x 512
  float* ssAll    = (float*)alloc(2048 * 4);
  unsigned short* Wblk = (unsigned short*)alloc(3 * 256 * 256 * 2);
  int* cntg    = (int*)alloc(2048 * 4);
  int* gstart  = (int*)alloc(2049 * 4);
  float* pooled = (float*)alloc((size_t)2048 * 512 * 4);
  float* s1b    = (float*)alloc((size_t)2048 * 256 * 4);
  (void)ws_size; (void)n_in; (void)out_size;

  int nb = (N + TPB - 1) / TPB;
  int eb = (E + TPB - 1) / TPB;
  int nblocks1 = (N + 1023) / 1024;

  k_init<<<nb, TPB, 0, stream>>>(dis, cnt, cntg, statsAll, statsP, N);
  k_hist<<<eb, TPB, 0, stream>>>(dstp, dis, cnt, batch, cntg, E, N);
  k_scan1<<<nblocks1, 256, 0, stream>>>(cnt, rs, bsum, N);
  k_scan_small2<<<2, 256, 0, stream>>>(bsum, bsumx, nblocks1, cntg, gstart, NGRAPH);
  k_scan3<<<nb, TPB, 0, stream>>>(rs, bsumx, cursor, dis, N, E);
  k_scatter<<<eb, TPB, 0, stream>>>(srcp, dstp, cursor, es, E);

  // weight prep (layers 2..4) in one launch: K=64-blocked + swizzle-baked bf16
  k_wprep2<<<768, 256, 0, stream>>>(W2, W3, W4, Wblk);

  // ---- layer 1: fused aggregate(D=8) + project (fp32) + BN stats ----
  k_gemm8<<<(N + 63) / 64, 256, 0, stream>>>(x, dis, rs, es, W1, b1, Ybf,
                                             statsAll, N);
  k_scaleshift<<<1, 256, 0, stream>>>(statsAll, 1, g1, be1, ssAll, N);

  // ---- layers 2..4 ----
  const float* bs_[3] = {b2, b3, b4};
  const float* gs[3]  = {g2, g3, g4};
  const float* bes[3] = {be2, be3, be4};
  for (int L = 0; L < 3; ++L) {
    k_agg_bn<<<(N + 7) / 8, 256, 0, stream>>>(Ybf, ssAll + L * 512, dis, rs, es,
                                              Ahi, N);
    k_gemm_mfma<<<(N + 63) / 64, 256, 0, stream>>>(Ahi, Wblk + L * 65536,
                                                   bs_[L], Ybf, statsP + L * 4096, N);
    k_scaleshift<<<1, 256, 0, stream>>>(statsP + L * 4096, 8, gs[L], bes[L],
                                        ssAll + (L + 1) * 512, N);
  }

  // ---- pooling (fused BN+ReLU of layer 4) + MLP + fused tail ----
  k_pool<<<NGRAPH, 256, 0, stream>>>(Ybf, ssAll + 3 * 512, gstart, pooled);
  k_mlp1<<<NGRAPH / 4, 256, 0, stream>>>(pooled, sW1, sb1, s1b);
  k_tail<<<NGRAPH / 2, 128, 0, stream>>>(s1b, sW2, sb2, hW1, hb1, hW2, hb2,
                                         (float*)d_out);
}

// Round 36
// 465.610 us; speedup vs baseline: 2.3066x; 1.0035x over previous
//
#include <hip/hip_runtime.h>
#include <math.h>

#define TPB 256
#define NGRAPH 2048

typedef __attribute__((ext_vector_type(8))) short bf16x8;
typedef __attribute__((ext_vector_type(4))) float f32x4;

__device__ __forceinline__ unsigned short f2bf(float f) {
  unsigned u = __float_as_uint(f);
  unsigned r = (u + 0x7FFF + ((u >> 16) & 1)) >> 16;
  return (unsigned short)r;
}
__device__ __forceinline__ float bf2f(unsigned short h) {
  return __uint_as_float(((unsigned)h) << 16);
}
__device__ __forceinline__ float bflo(unsigned u) {
  return __uint_as_float(u << 16);
}
__device__ __forceinline__ float bfhi(unsigned u) {
  return __uint_as_float(u & 0xFFFF0000u);
}

#define GLOAD_LDS16(G, L) \
  __builtin_amdgcn_global_load_lds((const __attribute__((address_space(1))) unsigned int*)(G), \
                                   (__attribute__((address_space(3))) unsigned int*)(L), 16, 0, 0)

// ---------------- init / degree / histograms ----------------
__global__ void k_init(float* __restrict__ deg, int* __restrict__ cnt,
                       int* __restrict__ cntg, float* __restrict__ statsAll,
                       float* __restrict__ statsP, int N) {
  int i = blockIdx.x * TPB + threadIdx.x;
  if (i < N) { deg[i] = 1.0f; cnt[i] = 0; }
  if (i < NGRAPH) cntg[i] = 0;
  if (i < 2048) statsAll[i] = 0.f;
  if (i < 12288) statsP[i] = 0.f;
}

// fused: edge-degree histogram (over E) + graph-size histogram (over N)
__global__ void k_hist(const int* __restrict__ dst, float* __restrict__ deg,
                       int* __restrict__ cnt, const int* __restrict__ batch,
                       int* __restrict__ cntg, int E, int N) {
  int i = blockIdx.x * TPB + threadIdx.x;
  if (i < E) {
    int d = dst[i];
    atomicAdd(&deg[d], 1.0f);
    atomicAdd(&cnt[d], 1);
  }
  if (i < N) atomicAdd(&cntg[batch[i]], 1);
}

// ---------------- scans ----------------
__global__ void k_scan1(const int* __restrict__ in, int* __restrict__ out,
                        int* __restrict__ bsum, int n) {
  __shared__ int ts[256];
  int tid = threadIdx.x;
  int base = blockIdx.x * 1024 + tid * 4;
  int v0 = (base + 0 < n) ? in[base + 0] : 0;
  int v1 = (base + 1 < n) ? in[base + 1] : 0;
  int v2 = (base + 2 < n) ? in[base + 2] : 0;
  int v3 = (base + 3 < n) ? in[base + 3] : 0;
  int s = v0 + v1 + v2 + v3;
  int run = s;
  ts[tid] = run; __syncthreads();
  for (int off = 1; off < 256; off <<= 1) {
    int add = (tid >= off) ? ts[tid - off] : 0;
    __syncthreads();
    run += add; ts[tid] = run; __syncthreads();
  }
  int acc = run - s;
  if (base + 0 < n) out[base + 0] = acc; acc += v0;
  if (base + 1 < n) out[base + 1] = acc; acc += v1;
  if (base + 2 < n) out[base + 2] = acc; acc += v2;
  if (base + 3 < n) out[base + 3] = acc;
  if (tid == 255) bsum[blockIdx.x] = run;
}

// dual single-block exclusive scan: block 0 scans (inA,nA)->dstA, block 1
// scans (inB,nB)->dstB. Both inputs are ready when this launches.
__global__ void k_scan_small2(const int* __restrict__ inA, int* __restrict__ dstA, int nA,
                              const int* __restrict__ inB, int* __restrict__ dstB, int nB) {
  __shared__ int ts[256];
  const int* in = (blockIdx.x == 0) ? inA : inB;
  int* dst      = (blockIdx.x == 0) ? dstA : dstB;
  int n         = (blockIdx.x == 0) ? nA : nB;
  int tid = threadIdx.x;
  int chunk = (n + 255) >> 8;
  int start = tid * chunk;
  int s = 0;
  for (int j = 0; j < chunk; ++j) { int idx = start + j; if (idx < n) s += in[idx]; }
  int run = s;
  ts[tid] = run; __syncthreads();
  for (int off = 1; off < 256; off <<= 1) {
    int add = (tid >= off) ? ts[tid - off] : 0;
    __syncthreads();
    run += add; ts[tid] = run; __syncthreads();
  }
  int acc = run - s;
  for (int j = 0; j < chunk; ++j) {
    int idx = start + j;
    if (idx < n) { dst[idx] = acc; acc += in[idx]; }
  }
  if (tid == 255) dst[n] = run;
}

// scan finalize + fused rsqrt(deg) -> dis (deg final since k_hist completed)
__global__ void k_scan3(int* __restrict__ rs, const int* __restrict__ bsumx,
                        int* __restrict__ cursor, float* __restrict__ dis,
                        int n, int total) {
  int i = blockIdx.x * TPB + threadIdx.x;
  if (i < n) {
    int v = rs[i] + bsumx[i >> 10];
    rs[i] = v; cursor[i] = v;
    dis[i] = rsqrtf(dis[i]);
  }
  if (i == 0) rs[n] = total;
}

__global__ void k_scatter(const int* __restrict__ src, const int* __restrict__ dst,
                          int* __restrict__ cursor, int* __restrict__ es, int E) {
  int e = blockIdx.x * TPB + threadIdx.x;
  if (e < E) {
    int d = dst[e];
    int p = atomicAdd(&cursor[d], 1);
    es[p] = src[e];
  }
}

// ------- weight prep: all 3 layers in one launch (grid 768) ----------------
// K=64-blocked transposed layout, swizzle pre-baked.
__global__ __launch_bounds__(256) void k_wprep2(const float* __restrict__ W2,
    const float* __restrict__ W3, const float* __restrict__ W4,
    unsigned short* __restrict__ Wblk) {
  int L = blockIdx.x >> 8;          // 0..2
  int c = blockIdx.x & 255;
  int k = threadIdx.x;
  const float* W = (L == 0) ? W2 : (L == 1) ? W3 : W4;
  float w = W[k * 256 + c];
  int t = k >> 6, kl = k & 63;
  Wblk[L * 65536 + t * 16384 + c * 64 + (kl ^ ((c & 7) << 3))] = f2bf(w);
}

// ---- layer 1 fused: aggregate on D=8 inline + project + BN stats ----------
// Edge loop unrolled 2-wide (loads paired, fmaf chain ordered -> same math).
__global__ __launch_bounds__(256) void k_gemm8(const float* __restrict__ x,
    const float* __restrict__ dis, const int* __restrict__ rs,
    const int* __restrict__ es,
    const float* __restrict__ W, const float* __restrict__ b,
    unsigned short* __restrict__ Ybf, float* __restrict__ stats, int N) {
  __shared__ float Ws[8 * 256];
  __shared__ float bs[256];
  __shared__ float rows[64 * 8];
  int tid = threadIdx.x;
  int row0 = blockIdx.x * 64;
  for (int j = 0; j < 8; ++j) Ws[tid + j * 256] = W[tid + j * 256];
  bs[tid] = b[tid];
#pragma unroll
  for (int half = 0; half < 2; ++half) {
    int idx = tid + half * 256;
    int n = row0 + (idx >> 3);
    int c = idx & 7;
    float val = 0.f;
    if (n < N) {
      int e0 = rs[n], e1 = rs[n + 1];
      float acc = 0.f;
      int e = e0;
      for (; e + 2 <= e1; e += 2) {
        int s0 = es[e], s1 = es[e + 1];
        float d0 = dis[s0], d1 = dis[s1];
        float x0 = x[s0 * 8 + c], x1 = x[s1 * 8 + c];
        acc = fmaf(d0, x0, acc);
        acc = fmaf(d1, x1, acc);
      }
      if (e < e1) {
        int s0 = es[e];
        acc = fmaf(dis[s0], x[s0 * 8 + c], acc);
      }
      float dn = dis[n];
      val = dn * acc + dn * dn * x[n * 8 + c];
    }
    rows[idx] = val;
  }
  __syncthreads();
  float bb = bs[tid];
  float s = 0.f, s2 = 0.f;
  for (int r = 0; r < 64; r += 2) {
    int rowA = row0 + r, rowB = rowA + 1;
    float a0 = bb, a1 = bb;
#pragma unroll
    for (int k = 0; k < 8; ++k) {
      a0 = fmaf(rows[r * 8 + k], Ws[k * 256 + tid], a0);
      a1 = fmaf(rows[r * 8 + 8 + k], Ws[k * 256 + tid], a1);
    }
    if (rowA < N) {
      Ybf[(size_t)rowA * 256 + tid] = f2bf(a0);
      s += a0; s2 += a0 * a0;
    }
    if (rowB < N) {
      Ybf[(size_t)rowB * 256 + tid] = f2bf(a1);
      s += a1; s2 += a1 * a1;
    }
  }
  atomicAdd(&stats[tid], s);
  atomicAdd(&stats[256 + tid], s2);
}

// ------- fused BN+ReLU aggregation, half-wave per node (r22-measured) ------
__global__ __launch_bounds__(256) void k_agg_bn(const unsigned short* __restrict__ Ybf,
    const float* __restrict__ ss, const float* __restrict__ dis,
    const int* __restrict__ rs, const int* __restrict__ es,
    unsigned short* __restrict__ Ahi, int N) {
  int l32 = threadIdx.x & 31;
  int n = blockIdx.x * 8 + (threadIdx.x >> 5);
  if (n >= N) return;
  int c = l32 * 8;
  float4 sc0 = *(const float4*)&ss[c];
  float4 sc1 = *(const float4*)&ss[c + 4];
  float4 sh0 = *(const float4*)&ss[256 + c];
  float4 sh1 = *(const float4*)&ss[256 + c + 4];
  int e0 = rs[n], e1 = rs[n + 1];
  float a0 = 0.f, a1 = 0.f, a2 = 0.f, a3 = 0.f;
  float a4 = 0.f, a5 = 0.f, a6 = 0.f, a7 = 0.f;
#define BNR8(Q, d)                                                           \
  {                                                                          \
    a0 += (d) * fmaxf(fmaf(bflo(Q.x), sc0.x, sh0.x), 0.f);                   \
    a1 += (d) * fmaxf(fmaf(bfhi(Q.x), sc0.y, sh0.y), 0.f);                   \
    a2 += (d) * fmaxf(fmaf(bflo(Q.y), sc0.z, sh0.z), 0.f);                   \
    a3 += (d) * fmaxf(fmaf(bfhi(Q.y), sc0.w, sh0.w), 0.f);                   \
    a4 += (d) * fmaxf(fmaf(bflo(Q.z), sc1.x, sh1.x), 0.f);                   \
    a5 += (d) * fmaxf(fmaf(bfhi(Q.z), sc1.y, sh1.y), 0.f);                   \
    a6 += (d) * fmaxf(fmaf(bflo(Q.w), sc1.z, sh1.z), 0.f);                   \
    a7 += (d) * fmaxf(fmaf(bfhi(Q.w), sc1.w, sh1.w), 0.f);                   \
  }
  int e = e0;
  for (; e + 2 <= e1; e += 2) {
    int s0 = es[e], s1 = es[e + 1];
    float d0 = dis[s0], d1 = dis[s1];
    uint4 y0 = *(const uint4*)&Ybf[(size_t)s0 * 256 + c];
    uint4 y1 = *(const uint4*)&Ybf[(size_t)s1 * 256 + c];
    BNR8(y0, d0);
    BNR8(y1, d1);
  }
  if (e < e1) {
    int s0 = es[e];
    float d0 = dis[s0];
    uint4 y0 = *(const uint4*)&Ybf[(size_t)s0 * 256 + c];
    BNR8(y0, d0);
  }
#undef BNR8
  float dn = dis[n];
  float dn2 = dn * dn;
  uint4 yb = *(const uint4*)&Ybf[(size_t)n * 256 + c];
  float r0 = dn * a0 + dn2 * fmaxf(fmaf(bflo(yb.x), sc0.x, sh0.x), 0.f);
  float r1 = dn * a1 + dn2 * fmaxf(fmaf(bfhi(yb.x), sc0.y, sh0.y), 0.f);
  float r2 = dn * a2 + dn2 * fmaxf(fmaf(bflo(yb.y), sc0.z, sh0.z), 0.f);
  float r3 = dn * a3 + dn2 * fmaxf(fmaf(bfhi(yb.y), sc0.w, sh0.w), 0.f);
  float r4 = dn * a4 + dn2 * fmaxf(fmaf(bflo(yb.z), sc1.x, sh1.x), 0.f);
  float r5 = dn * a5 + dn2 * fmaxf(fmaf(bfhi(yb.z), sc1.y, sh1.y), 0.f);
  float r6 = dn * a6 + dn2 * fmaxf(fmaf(bflo(yb.w), sc1.z, sh1.z), 0.f);
  float r7 = dn * a7 + dn2 * fmaxf(fmaf(bfhi(yb.w), sc1.w, sh1.w), 0.f);
  uint4 o;
  o.x = (unsigned)f2bf(r0) | ((unsigned)f2bf(r1) << 16);
  o.y = (unsigned)f2bf(r2) | ((unsigned)f2bf(r3) << 16);
  o.z = (unsigned)f2bf(r4) | ((unsigned)f2bf(r5) << 16);
  o.w = (unsigned)f2bf(r6) | ((unsigned)f2bf(r7) << 16);
  *(uint4*)&Ahi[(size_t)n * 256 + c] = o;
}

// ---------------- MFMA GEMM (r20/r26-measured best: ~55us @29% occ) -------
__global__ __launch_bounds__(256) void k_gemm_mfma(
    const unsigned short* __restrict__ A,
    const unsigned short* __restrict__ Wblk,
    const float* __restrict__ bias, unsigned short* __restrict__ Ybf,
    float* __restrict__ statsP, int M) {
  __shared__ unsigned short Wlds[16384];  // 32KB W slab / epilogue stage
  __shared__ float bstats[512];
  const int tid = threadIdx.x;
  const int lane = tid & 63;
  const int w = tid >> 6;
  const int l15 = lane & 15, lg = lane >> 4;
  const int r0 = blockIdx.x * 64 + w * 16;

  bstats[tid] = 0.f;
  bstats[tid + 256] = 0.f;

  const unsigned short* Ap = A + (size_t)(r0 + l15) * 256 + lg * 8;

  f32x4 acc[16] = {};
#pragma unroll
  for (int t = 0; t < 4; ++t) {
#pragma unroll
    for (int it = 0; it < 8; ++it)
      GLOAD_LDS16(Wblk + t * 16384 + it * 2048 + tid * 8,
                  &Wlds[it * 2048 + tid * 8]);
    bf16x8 a0 = *(const bf16x8*)(Ap + t * 64);
    bf16x8 a1 = *(const bf16x8*)(Ap + t * 64 + 32);
    asm volatile("s_waitcnt vmcnt(0)" ::: "memory");
    __builtin_amdgcn_s_barrier();
#pragma unroll
    for (int kk2 = 0; kk2 < 2; ++kk2) {
      bf16x8 a = kk2 ? a1 : a0;
#pragma unroll
      for (int n = 0; n < 16; ++n) {
        int c = n * 16 + l15;
        bf16x8 b = *(const bf16x8*)&Wlds[c * 64 +
                     ((kk2 * 32 + lg * 8) ^ ((l15 & 7) << 3))];
        acc[n] = __builtin_amdgcn_mfma_f32_16x16x32_bf16(a, b, acc[n], 0, 0, 0);
      }
    }
    asm volatile("s_waitcnt lgkmcnt(0)" ::: "memory");
    __builtin_amdgcn_s_barrier();
  }

  unsigned short* stage = Wlds;  // 64 rows x 256 cols bf16 = 32KB
#pragma unroll
  for (int n = 0; n < 16; ++n) {
    int col = n * 16 + l15;
    float bv = bias[col];
    float s = 0.f, s2 = 0.f;
    f32x4 v = acc[n];
#pragma unroll
    for (int j = 0; j < 4; ++j) {
      float val = v[j] + bv;
      int rl = w * 16 + lg * 4 + j;
      stage[rl * 256 + col] = f2bf(val);
      if (blockIdx.x * 64 + rl < M) { s += val; s2 += val * val; }
    }
    s += __shfl_xor(s, 16);  s += __shfl_xor(s, 32);
    s2 += __shfl_xor(s2, 16); s2 += __shfl_xor(s2, 32);
    if (lg == 0) {
      atomicAdd(&bstats[col], s);
      atomicAdd(&bstats[256 + col], s2);
    }
  }
  __syncthreads();
#pragma unroll
  for (int it = 0; it < 8; ++it) {
    int idx = it * 256 + tid;
    int rl = idx >> 5;
    int c16 = idx & 31;
    int grow = blockIdx.x * 64 + rl;
    if (grow < M)
      *(int4*)((char*)Ybf + (size_t)grow * 512 + c16 * 16) =
          *(const int4*)((const char*)stage + rl * 512 + c16 * 16);
  }
  float* sp = statsP + (blockIdx.x & 7) * 512;
  atomicAdd(&sp[tid], bstats[tid]);
  atomicAdd(&sp[256 + tid], bstats[256 + tid]);
}

// ---------------- BN scale/shift (sums npart partial slices) ----------------
__global__ void k_scaleshift(const float* __restrict__ base, int npart,
                             const float* __restrict__ g,
                             const float* __restrict__ be, float* __restrict__ ss, int N) {
  int c = threadIdx.x;
  float s = 0.f, s2 = 0.f;
  for (int p = 0; p < npart; ++p) {
    s += base[p * 512 + c];
    s2 += base[p * 512 + 256 + c];
  }
  float inv = 1.0f / (float)N;
  float mean = s * inv;
  float var = s2 * inv - mean * mean;
  var = fmaxf(var, 0.f);
  float sc = g[c] * rsqrtf(var + 1e-5f);
  ss[c] = sc;
  ss[256 + c] = be[c] - mean * sc;
}

// ---------------- pooling with fused BN+ReLU, vectorized (r29-measured) -----
__global__ __launch_bounds__(256) void k_pool(const unsigned short* __restrict__ Ybf,
    const float* __restrict__ ss, const int* __restrict__ gstart,
    float* __restrict__ pooled) {
  __shared__ float redS[8][256];
  __shared__ float redM[8][256];
  int g = blockIdx.x;
  int tid = threadIdx.x;
  int grp = tid >> 5;      // 0..7 row-group
  int l32 = tid & 31;
  int c = l32 * 8;
  float4 sc0 = *(const float4*)&ss[c];
  float4 sc1 = *(const float4*)&ss[c + 4];
  float4 sh0 = *(const float4*)&ss[256 + c];
  float4 sh1 = *(const float4*)&ss[256 + c + 4];
  int n0 = gstart[g], n1 = gstart[g + 1];
  float s0 = 0.f, s1 = 0.f, s2 = 0.f, s3 = 0.f, s4 = 0.f, s5 = 0.f, s6 = 0.f, s7 = 0.f;
  float m0 = 0.f, m1 = 0.f, m2 = 0.f, m3 = 0.f, m4 = 0.f, m5 = 0.f, m6 = 0.f, m7 = 0.f;
  for (int n = n0 + grp; n < n1; n += 8) {
    uint4 y = *(const uint4*)&Ybf[(size_t)n * 256 + c];
    float v0 = fmaxf(fmaf(bflo(y.x), sc0.x, sh0.x), 0.f);
    float v1 = fmaxf(fmaf(bfhi(y.x), sc0.y, sh0.y), 0.f);
    float v2 = fmaxf(fmaf(bflo(y.y), sc0.z, sh0.z), 0.f);
    float v3 = fmaxf(fmaf(bfhi(y.y), sc0.w, sh0.w), 0.f);
    float v4 = fmaxf(fmaf(bflo(y.z), sc1.x, sh1.x), 0.f);
    float v5 = fmaxf(fmaf(bfhi(y.z), sc1.y, sh1.y), 0.f);
    float v6 = fmaxf(fmaf(bflo(y.w), sc1.z, sh1.z), 0.f);
    float v7 = fmaxf(fmaf(bfhi(y.w), sc1.w, sh1.w), 0.f);
    s0 += v0; m0 = fmaxf(m0, v0);
    s1 += v1; m1 = fmaxf(m1, v1);
    s2 += v2; m2 = fmaxf(m2, v2);
    s3 += v3; m3 = fmaxf(m3, v3);
    s4 += v4; m4 = fmaxf(m4, v4);
    s5 += v5; m5 = fmaxf(m5, v5);
    s6 += v6; m6 = fmaxf(m6, v6);
    s7 += v7; m7 = fmaxf(m7, v7);
  }
  redS[grp][c + 0] = s0; redM[grp][c + 0] = m0;
  redS[grp][c + 1] = s1; redM[grp][c + 1] = m1;
  redS[grp][c + 2] = s2; redM[grp][c + 2] = m2;
  redS[grp][c + 3] = s3; redM[grp][c + 3] = m3;
  redS[grp][c + 4] = s4; redM[grp][c + 4] = m4;
  redS[grp][c + 5] = s5; redM[grp][c + 5] = m5;
  redS[grp][c + 6] = s6; redM[grp][c + 6] = m6;
  redS[grp][c + 7] = s7; redM[grp][c + 7] = m7;
  __syncthreads();
  float s = 0.f, m = 0.f;
#pragma unroll
  for (int k = 0; k < 8; ++k) {
    s += redS[k][tid];
    m = fmaxf(m, redM[k][tid]);
  }
  float cnt = (float)(n1 - n0);
  pooled[g * 512 + tid] = s / fmaxf(cnt, 1.0f);
  pooled[g * 512 + 256 + tid] = m;
}

// ---------------- MLP + fused tail (mlp2 + heads) ----------------
__global__ __launch_bounds__(256) void k_mlp1(const float* __restrict__ P,
    const float* __restrict__ W, const float* __restrict__ b, float* __restrict__ O) {
  __shared__ float Ps[4 * 512];
  int tid = threadIdx.x;
  int g0 = blockIdx.x * 4;
  for (int j = 0; j < 8; ++j) Ps[j * 256 + tid] = P[g0 * 512 + j * 256 + tid];
  __syncthreads();
  float acc[4];
  float bb = b[tid];
#pragma unroll
  for (int gi = 0; gi < 4; ++gi) acc[gi] = bb;
  for (int k = 0; k < 512; ++k) {
    float w = W[k * 256 + tid];
#pragma unroll
    for (int gi = 0; gi < 4; ++gi) acc[gi] += Ps[gi * 512 + k] * w;
  }
#pragma unroll
  for (int gi = 0; gi < 4; ++gi)
    O[(g0 + gi) * 256 + tid] = fmaxf(acc[gi], 0.f);
}

// fused mlp2 + heads: 2 graphs per block, 128 threads.
__global__ __launch_bounds__(128) void k_tail(const float* __restrict__ S,
    const float* __restrict__ W, const float* __restrict__ b,
    const float* __restrict__ hW1, const float* __restrict__ hb1,
    const float* __restrict__ hW2, const float* __restrict__ hb2,
    float* __restrict__ out) {
  __shared__ float Ss[2 * 256];
  __shared__ float s2s[2][128];
  __shared__ float t1s[2][96];
  int tid = threadIdx.x;
  int g0 = blockIdx.x * 2;
  for (int j = 0; j < 4; ++j) Ss[j * 128 + tid] = S[g0 * 256 + j * 128 + tid];
  __syncthreads();
  float bb = b[tid];
  float acc0 = bb, acc1 = bb;
  for (int k = 0; k < 256; ++k) {
    float w = W[k * 128 + tid];
    acc0 += Ss[k] * w;
    acc1 += Ss[256 + k] * w;
  }
  s2s[0][tid] = fmaxf(acc0, 0.f);
  s2s[1][tid] = fmaxf(acc1, 0.f);
  __syncthreads();
  if (tid < 96) {
    int t = tid >> 5, o = tid & 31;
    float hb = hb1[t * 32 + o];
    float a0 = hb, a1 = hb;
    for (int k = 0; k < 128; ++k) {
      float w = hW1[t * 4096 + k * 32 + o];
      a0 += s2s[0][k] * w;
      a1 += s2s[1][k] * w;
    }
    t1s[0][tid] = fmaxf(a0, 0.f);
    t1s[1][tid] = fmaxf(a1, 0.f);
  }
  __syncthreads();
  if (tid < 6) {
    int p = tid / 3, t = tid - p * 3;
    float acc = hb2[t];
    for (int o = 0; o < 32; ++o) acc += t1s[p][t * 32 + o] * hW2[t * 32 + o];
    out[t * NGRAPH + g0 + p] = acc;
  }
}

// ---------------- host launcher ----------------
extern "C" void kernel_launch(void* const* d_in, const int* in_sizes, int n_in,
                              void* d_out, int out_size, void* d_ws, size_t ws_size,
                              hipStream_t stream) {
  const float* x   = (const float*)d_in[0];
  const int* ei    = (const int*)d_in[1];
  const int* batch = (const int*)d_in[2];
  const float* W1 = (const float*)d_in[3];  const float* b1 = (const float*)d_in[4];
  const float* W2 = (const float*)d_in[5];  const float* b2 = (const float*)d_in[6];
  const float* W3 = (const float*)d_in[7];  const float* b3 = (const float*)d_in[8];
  const float* W4 = (const float*)d_in[9];  const float* b4 = (const float*)d_in[10];
  const float* g1 = (const float*)d_in[11]; const float* be1 = (const float*)d_in[12];
  const float* g2 = (const float*)d_in[13]; const float* be2 = (const float*)d_in[14];
  const float* g3 = (const float*)d_in[15]; const float* be3 = (const float*)d_in[16];
  const float* g4 = (const float*)d_in[17]; const float* be4 = (const float*)d_in[18];
  const float* sW1 = (const float*)d_in[19]; const float* sb1 = (const float*)d_in[20];
  const float* sW2 = (const float*)d_in[21]; const float* sb2 = (const float*)d_in[22];
  const float* hW1 = (const float*)d_in[23]; const float* hb1 = (const float*)d_in[24];
  const float* hW2 = (const float*)d_in[25]; const float* hb2 = (const float*)d_in[26];

  const int N = in_sizes[0] / 8;
  const int E = in_sizes[1] / 2;
  const int Npad = (N + 127) & ~127;
  const int* srcp = ei;
  const int* dstp = ei + E;

  char* base = (char*)d_ws;
  size_t off = 0;
  auto alloc = [&](size_t bytes) -> void* {
    void* p = base + off;
    off += (bytes + 255) & ~(size_t)255;
    return p;
  };
  unsigned short* Ybf = (unsigned short*)alloc((size_t)Npad * 256 * 2);
  unsigned short* Ahi = (unsigned short*)alloc((size_t)Npad * 256 * 2);
  float* dis  = (float*)alloc((size_t)N * 4);
  int* cnt    = (int*)alloc((size_t)N * 4);
  int* rs     = (int*)alloc((size_t)(N + 1) * 4);
  int* cursor = (int*)alloc((size_t)N * 4);
  int* es     = (int*)alloc((size_t)E * 4);
  int* bsum   = (int*)alloc(1024 * 4);
  int* bsumx  = (int*)alloc(1032 * 4);
  float* statsAll = (float*)alloc(2048 * 4);
  float* statsP   = (float*)alloc(12288 * 4);   // 3 layers x 8 slices x 512
  float* ssAll    = (float*)alloc(2048 * 4);
  unsigned short* Wblk = (unsigned short*)alloc(3 * 256 * 256 * 2);
  int* cntg    = (int*)alloc(2048 * 4);
  int* gstart  = (int*)alloc(2049 * 4);
  float* pooled = (float*)alloc((size_t)2048 * 512 * 4);
  float* s1b    = (float*)alloc((size_t)2048 * 256 * 4);
  (void)ws_size; (void)n_in; (void)out_size;

  int nb = (N + TPB - 1) / TPB;
  int eb = (E + TPB - 1) / TPB;
  int nblocks1 = (N + 1023) / 1024;

  k_init<<<nb, TPB, 0, stream>>>(dis, cnt, cntg, statsAll, statsP, N);
  k_hist<<<eb, TPB, 0, stream>>>(dstp, dis, cnt, batch, cntg, E, N);
  k_scan1<<<nblocks1, 256, 0, stream>>>(cnt, rs, bsum, N);
  k_scan_small2<<<2, 256, 0, stream>>>(bsum, bsumx, nblocks1, cntg, gstart, NGRAPH);
  k_scan3<<<nb, TPB, 0, stream>>>(rs, bsumx, cursor, dis, N, E);
  k_scatter<<<eb, TPB, 0, stream>>>(srcp, dstp, cursor, es, E);

  // weight prep (layers 2..4) in one launch: K=64-blocked + swizzle-baked bf16
  k_wprep2<<<768, 256, 0, stream>>>(W2, W3, W4, Wblk);

  // ---- layer 1: fused aggregate(D=8) + project (fp32) + BN stats ----
  k_gemm8<<<(N + 63) / 64, 256, 0, stream>>>(x, dis, rs, es, W1, b1, Ybf,
                                             statsAll, N);
  k_scaleshift<<<1, 256, 0, stream>>>(statsAll, 1, g1, be1, ssAll, N);

  // ---- layers 2..4 ----
  const float* bs_[3] = {b2, b3, b4};
  const float* gs[3]  = {g2, g3, g4};
  const float* bes[3] = {be2, be3, be4};
  for (int L = 0; L < 3; ++L) {
    k_agg_bn<<<(N + 7) / 8, 256, 0, stream>>>(Ybf, ssAll + L * 512, dis, rs, es,
                                              Ahi, N);
    k_gemm_mfma<<<(N + 63) / 64, 256, 0, stream>>>(Ahi, Wblk + L * 65536,
                                                   bs_[L], Ybf, statsP + L * 4096, N);
    k_scaleshift<<<1, 256, 0, stream>>>(statsP + L * 4096, 8, gs[L], bes[L],
                                        ssAll + (L + 1) * 512, N);
  }

  // ---- pooling (fused BN+ReLU of layer 4) + MLP + fused tail ----
  k_pool<<<NGRAPH, 256, 0, stream>>>(Ybf, ssAll + 3 * 512, gstart, pooled);
  k_mlp1<<<NGRAPH / 4, 256, 0, stream>>>(pooled, sW1, sb1, s1b);
  k_tail<<<NGRAPH / 2, 128, 0, stream>>>(s1b, sW2, sb2, hW1, hb1, hW2, hb2,
                                         (float*)d_out);
}